// Round 2
// baseline (473.648 us; speedup 1.0000x reference)
//
#include <hip/hip_runtime.h>
#include <hip/hip_fp16.h>
#include <cstdint>
#include <cstddef>

#define Nn 50000
#define Ne 800000
#define Ng 1024
#define NFd 32
#define Rr 4
#define Hd 64
#define Od 16
#define MAXD 10
#define NSEG (Nn * Rr)
#define SCAN_BLK ((NSEG + 255) / 256)
#define ORDER_SZ (Nn + 112)                // buckets padded to x8: max 11*7=77 pad, /32 exact
#define NB_MF (ORDER_SZ / 32)              // block = 4 waves x 8 slots
#define NB_RG ((Nn + 31) / 32)             // block = 4 waves x 8 nodes
#define NB_RELSEG (Ne / 256)               // 3125 edge blocks
#define NB_EMBED (Nn / 4)                  // 12500 embed blocks

__device__ __forceinline__ float reluf(float v) { return v > 0.f ? v : 0.f; }
__device__ __forceinline__ int rfl(int v) { return __builtin_amdgcn_readfirstlane(v); }

// ---- FUSED: per-edge relation argmax/histogram/rank  +  embedding lookup ----
// Embed writes fp32 h (root/transform path) + fp16 shadow (gather path).
__global__ void k_rel_emb(const float4* __restrict__ ea, const int* __restrict__ eidx,
                          int* __restrict__ seg, int* __restrict__ rank,
                          int* __restrict__ cnt,
                          const float* __restrict__ x, const float* __restrict__ emb,
                          float* __restrict__ h, __half* __restrict__ h16) {
    if (blockIdx.x < NB_RELSEG) {
        int e = blockIdx.x * 256 + threadIdx.x;     // grid sized exactly: e < Ne
        float4 a = ea[e];
        int bi = 0; float bv = a.x;
        if (a.y > bv) { bv = a.y; bi = 1; }
        if (a.z > bv) { bv = a.z; bi = 2; }
        if (a.w > bv) { bv = a.w; bi = 3; }
        int s = eidx[Ne + e] * Rr + bi;
        seg[e] = s;
        rank[e] = atomicAdd(&cnt[s], 1);
    } else {
        int wave = ((blockIdx.x - NB_RELSEG) * 256 + threadIdx.x) >> 6;  // < Nn
        int lane = threadIdx.x & 63;
        float v = (lane < NFd) ? x[(size_t)wave * NFd + lane] : -1e30f;
        int idx = lane;
        #pragma unroll
        for (int off = 16; off >= 1; off >>= 1) {
            float ov = __shfl_down(v, off);
            int oi = __shfl_down(idx, off);
            if (ov > v || (ov == v && oi < idx)) { v = ov; idx = oi; }
        }
        idx = __shfl(idx, 0);
        float hv = reluf(emb[(size_t)idx * Hd + lane]);
        h[(size_t)wave * Hd + lane] = hv;
        h16[(size_t)wave * Hd + lane] = __float2half(hv);
    }
}

// ---- scan level 1 + fused degree histogram (deg(n) = sum of its 4 cnt entries) ----
__global__ void k_scan1(const int* __restrict__ cnt, int* __restrict__ off,
                        int* __restrict__ bsum, int* __restrict__ bcnt) {
    __shared__ int s[256];
    __shared__ int hist[16];
    int t = threadIdx.x;
    if (t < 16) hist[t] = 0;
    int idx = blockIdx.x * 256 + t;
    int v = (idx < NSEG) ? cnt[idx] : 0;
    s[t] = v;
    __syncthreads();
    if ((t & 3) == 0 && idx < NSEG) {
        int dsum = s[t] + s[t + 1] + s[t + 2] + s[t + 3];
        atomicAdd(&hist[min(dsum, MAXD)], 1);
    }
    #pragma unroll
    for (int o = 1; o < 256; o <<= 1) {
        int x = (t >= o) ? s[t - o] : 0;
        __syncthreads();
        s[t] += x;
        __syncthreads();
    }
    if (idx < NSEG) off[idx] = s[t] - v;            // exclusive
    if (t == 255) bsum[blockIdx.x] = s[255];
    if (t < 16) {
        int h = hist[t];
        if (h > 0) atomicAdd(&bcnt[t], h);
    }
}

// ---- scan level 2 + fused bucket prefix (8-aligned) + order pad-slot writes ----
__global__ void k_scan2(int* __restrict__ bsum, const int* __restrict__ bcnt,
                        int* __restrict__ bbase, int* __restrict__ order) {
    __shared__ int s[1024];
    int t = threadIdx.x;
    int v = (t < SCAN_BLK) ? bsum[t] : 0;
    s[t] = v;
    __syncthreads();
    #pragma unroll
    for (int o = 1; o < 1024; o <<= 1) {
        int x = (t >= o) ? s[t - o] : 0;
        __syncthreads();
        s[t] += x;
        __syncthreads();
    }
    if (t < SCAN_BLK) bsum[t] = s[t] - v;           // exclusive block bases
    if (t == 0) {
        int run = 0;
        for (int d = 0; d <= MAXD; d++) {
            int c = bcnt[d];
            bbase[d] = run;
            int pad = (c + 7) & ~7;                 // x8: one wave = 8 uniform-d slots
            for (int i = c; i < pad; i++) order[run + i] = -1;
            run += pad;
        }
        for (int i = run; i < ORDER_SZ; i++) order[i] = -1;
    }
}

// ---- FUSED: scan level 3 (final off)  +  degree-bucket scatter (cnt-based) ----
__global__ void k_scan3_bucket(int* __restrict__ off, const int* __restrict__ bsum,
                               const int4* __restrict__ cnt4, const int* __restrict__ bbase,
                               int* __restrict__ bfill, int* __restrict__ order) {
    __shared__ int hist[16];
    __shared__ int base[16];
    int t = threadIdx.x;
    if (t < 16) hist[t] = 0;
    __syncthreads();
    int idx = blockIdx.x * 256 + t;
    if (idx == 0) off[NSEG] = Ne;
    if (idx < NSEG) off[idx] = off[idx] + bsum[blockIdx.x];
    int d = 0, rk = 0;
    bool valid = (idx < Nn);
    if (valid) {
        int4 c = cnt4[idx];
        d = min(c.x + c.y + c.z + c.w, MAXD);
        rk = atomicAdd(&hist[d], 1);
    }
    __syncthreads();
    if (t < 16) {
        int h = hist[t];
        base[t] = (h > 0) ? atomicAdd(&bfill[t], h) : 0;
    }
    __syncthreads();
    if (valid) order[bbase[d] + base[d] + rk] = idx | (d << 20);
}

// ---- scatter edges into segment-sorted order: NO atomics (rank precomputed) ----
__global__ void k_scatter(const int* __restrict__ eidx, const int* __restrict__ seg,
                          const int* __restrict__ rank, const int* __restrict__ off,
                          int* __restrict__ sorted_src) {
    int e = blockIdx.x * 256 + threadIdx.x;
    if (e >= Ne) return;
    int pos = off[seg[e]] + rank[e];
    sorted_src[pos] = eidx[e];
}

// classify edge ee via wave-uniform boundaries -> 4 uniform scalar scales
#define ACCS(v, ee)  {                                      \
    int rr = ((ee) >= e1) + ((ee) >= e2) + ((ee) >= e3);    \
    float s0 = (rr == 0) ? i0 : 0.f;                        \
    float s1 = (rr == 1) ? i1 : 0.f;                        \
    float s2 = (rr == 2) ? i2 : 0.f;                        \
    float s3 = (rr == 3) ? i3 : 0.f;                        \
    a0 = fmaf(s0, (v), a0);                                 \
    a1 = fmaf(s1, (v), a1);                                 \
    a2 = fmaf(s2, (v), a2);                                 \
    a3 = fmaf(s3, (v), a3); }

#define H16(ptr, s) __half2float((ptr)[(size_t)(s) * Hd + lane])

// ---- FUSED RGCN layer: 8 nodes/wave (halves per-wave weight redundancy) ----
// gather -> per-wave LDS means -> transform out = relu(bias + hin@Wroot + sum_r agg_r@W_r)
// wave-private LDS, no barrier; weights streamed from hot L2, amortized over 8 nodes.
__global__ __launch_bounds__(256) void k_rgcn_fused(
        const float* __restrict__ hin, const __half* __restrict__ hin16,
        const int* __restrict__ off, const int* __restrict__ ssrc,
        const float* __restrict__ W, const float* __restrict__ Wroot,
        const float* __restrict__ bias, float* __restrict__ hout,
        __half* __restrict__ hout16) {
    __shared__ float lds[4][8][Rr][Hd];             // 32 KB: [wave][node][rel][k]
    int tid = threadIdx.x;
    int wv = tid >> 6, lane = tid & 63;
    int n0 = rfl(blockIdx.x * 32 + wv * 8);
    for (int i = 0; i < 8; i++) {
        int n = n0 + i;
        if (n >= Nn) break;                         // tail block only
        int nb = n * Rr;
        int e0 = rfl(off[nb]);
        int e1 = rfl(off[nb + 1]);
        int e2 = rfl(off[nb + 2]);
        int e3 = rfl(off[nb + 3]);
        int e4 = rfl(off[nb + 4]);
        float i0 = (e1 > e0) ? 1.f / (float)(e1 - e0) : 0.f;
        float i1 = (e2 > e1) ? 1.f / (float)(e2 - e1) : 0.f;
        float i2 = (e3 > e2) ? 1.f / (float)(e3 - e2) : 0.f;
        float i3 = (e4 > e3) ? 1.f / (float)(e4 - e3) : 0.f;
        float a0 = 0.f, a1 = 0.f, a2 = 0.f, a3 = 0.f;
        int e = e0;
        for (; e + 16 <= e4; e += 16) {             // 16 loads in flight
            const int4 sA = *(const int4*)(ssrc + e);
            const int4 sB = *(const int4*)(ssrc + e + 4);
            const int4 sC = *(const int4*)(ssrc + e + 8);
            const int4 sD = *(const int4*)(ssrc + e + 12);
            float v0 = H16(hin16, sA.x);
            float v1 = H16(hin16, sA.y);
            float v2 = H16(hin16, sA.z);
            float v3 = H16(hin16, sA.w);
            float v4 = H16(hin16, sB.x);
            float v5 = H16(hin16, sB.y);
            float v6 = H16(hin16, sB.z);
            float v7 = H16(hin16, sB.w);
            float v8 = H16(hin16, sC.x);
            float v9 = H16(hin16, sC.y);
            float vA = H16(hin16, sC.z);
            float vB = H16(hin16, sC.w);
            float vC = H16(hin16, sD.x);
            float vD = H16(hin16, sD.y);
            float vE = H16(hin16, sD.z);
            float vF = H16(hin16, sD.w);
            ACCS(v0, e + 0);  ACCS(v1, e + 1);  ACCS(v2, e + 2);  ACCS(v3, e + 3);
            ACCS(v4, e + 4);  ACCS(v5, e + 5);  ACCS(v6, e + 6);  ACCS(v7, e + 7);
            ACCS(v8, e + 8);  ACCS(v9, e + 9);  ACCS(vA, e + 10); ACCS(vB, e + 11);
            ACCS(vC, e + 12); ACCS(vD, e + 13); ACCS(vE, e + 14); ACCS(vF, e + 15);
        }
        for (; e + 4 <= e4; e += 4) {
            const int4 sA = *(const int4*)(ssrc + e);
            float v0 = H16(hin16, sA.x);
            float v1 = H16(hin16, sA.y);
            float v2 = H16(hin16, sA.z);
            float v3 = H16(hin16, sA.w);
            ACCS(v0, e + 0); ACCS(v1, e + 1); ACCS(v2, e + 2); ACCS(v3, e + 3);
        }
        for (; e < e4; e++) {
            int s = rfl(ssrc[e]);
            float v = H16(hin16, s);
            ACCS(v, e);
        }
        lds[wv][i][0][lane] = a0;                   // wave-private: no barrier needed
        lds[wv][i][1][lane] = a1;
        lds[wv][i][2][lane] = a2;
        lds[wv][i][3][lane] = a3;
    }
    // in-kernel transform: acc[i][j=lane] = hin[n]@Wroot + sum_r a_r@W_r
    float acc[8] = {0.f, 0.f, 0.f, 0.f, 0.f, 0.f, 0.f, 0.f};
    for (int kc = 0; kc < Hd; kc += 4) {
        float r0 = Wroot[(kc + 0) * Hd + lane];
        float r1 = Wroot[(kc + 1) * Hd + lane];
        float r2 = Wroot[(kc + 2) * Hd + lane];
        float r3 = Wroot[(kc + 3) * Hd + lane];
        float w[4][4];
        #pragma unroll
        for (int rr = 0; rr < 4; rr++) {
            const float* wp = W + ((size_t)rr * Hd + kc) * Hd + lane;
            w[rr][0] = wp[0 * Hd];
            w[rr][1] = wp[1 * Hd];
            w[rr][2] = wp[2 * Hd];
            w[rr][3] = wp[3 * Hd];
        }
        #pragma unroll
        for (int i = 0; i < 8; i++) {
            const float4 hv  = *(const float4*)(hin + (size_t)(n0 + i) * Hd + kc);
            const float4 a0v = *(const float4*)&lds[wv][i][0][kc];
            const float4 a1v = *(const float4*)&lds[wv][i][1][kc];
            const float4 a2v = *(const float4*)&lds[wv][i][2][kc];
            const float4 a3v = *(const float4*)&lds[wv][i][3][kc];
            acc[i] += hv.x * r0 + hv.y * r1 + hv.z * r2 + hv.w * r3
                    + a0v.x * w[0][0] + a0v.y * w[0][1] + a0v.z * w[0][2] + a0v.w * w[0][3]
                    + a1v.x * w[1][0] + a1v.y * w[1][1] + a1v.z * w[1][2] + a1v.w * w[1][3]
                    + a2v.x * w[2][0] + a2v.y * w[2][1] + a2v.z * w[2][2] + a2v.w * w[2][3]
                    + a3v.x * w[3][0] + a3v.y * w[3][1] + a3v.z * w[3][2] + a3v.w * w[3][3];
        }
    }
    float bb = bias[lane];
    #pragma unroll
    for (int i = 0; i < 8; i++) {
        int n = n0 + i;
        if (n < Nn) {
            float v = reluf(acc[i] + bb);
            hout[(size_t)n * Hd + lane] = v;
            hout16[(size_t)n * Hd + lane] = __float2half(v);
        }
    }
}

// ---- FUSED MFConv layer: 8 slots/wave (buckets 8-aligned -> wave-uniform d) ----
// gather + degree-bucketed transform; weights streamed from hot L2, amortized x8.
__global__ __launch_bounds__(256) void k_mf_fused(
        const float* __restrict__ hin, const __half* __restrict__ hin16,
        const int* __restrict__ off, const int* __restrict__ ssrc,
        const int* __restrict__ order, const float* __restrict__ Wl,
        const float* __restrict__ bl, const float* __restrict__ Wr,
        float* __restrict__ hout, __half* __restrict__ hout16, int relu_out) {
    __shared__ float lds[4][8][Hd];                 // 8 KB: [wave][node][k]
    int tid = threadIdx.x;
    int wv = tid >> 6, lane = tid & 63;
    int slot0 = rfl(blockIdx.x * 32 + wv * 8);
    int ent[8];
    #pragma unroll
    for (int i = 0; i < 8; i++) ent[i] = rfl(order[slot0 + i]);
    int d = -1;
    #pragma unroll
    for (int i = 7; i >= 0; i--) if (ent[i] >= 0) d = ent[i] >> 20;
    if (d < 0) return;
    int n[8];
    #pragma unroll
    for (int i = 0; i < 8; i++) n[i] = (ent[i] >= 0) ? (ent[i] & 0xFFFFF) : 0;
    for (int i = 0; i < 8; i++) {
        int e0 = rfl(off[n[i] * Rr]);
        int e4 = rfl(off[n[i] * Rr + Rr]);
        float p0 = 0.f, p1 = 0.f, p2 = 0.f, p3 = 0.f;
        int e = e0;
        for (; e + 16 <= e4; e += 16) {
            const int4 sA = *(const int4*)(ssrc + e);
            const int4 sB = *(const int4*)(ssrc + e + 4);
            const int4 sC = *(const int4*)(ssrc + e + 8);
            const int4 sD = *(const int4*)(ssrc + e + 12);
            p0 += H16(hin16, sA.x) + H16(hin16, sA.y) + H16(hin16, sA.z) + H16(hin16, sA.w);
            p1 += H16(hin16, sB.x) + H16(hin16, sB.y) + H16(hin16, sB.z) + H16(hin16, sB.w);
            p2 += H16(hin16, sC.x) + H16(hin16, sC.y) + H16(hin16, sC.z) + H16(hin16, sC.w);
            p3 += H16(hin16, sD.x) + H16(hin16, sD.y) + H16(hin16, sD.z) + H16(hin16, sD.w);
        }
        for (; e + 4 <= e4; e += 4) {
            const int4 sA = *(const int4*)(ssrc + e);
            p0 += H16(hin16, sA.x) + H16(hin16, sA.y) + H16(hin16, sA.z) + H16(hin16, sA.w);
        }
        for (; e < e4; e++) {
            int s = rfl(ssrc[e]);
            p0 += H16(hin16, s);
        }
        lds[wv][i][lane] = (p0 + p1) + (p2 + p3);
    }
    const float* wl = Wl + (size_t)d * Hd * Hd;
    const float* wr = Wr + (size_t)d * Hd * Hd;
    float acc[8] = {0.f, 0.f, 0.f, 0.f, 0.f, 0.f, 0.f, 0.f};
    for (int kc = 0; kc < Hd; kc += 4) {
        float a0 = wl[(kc + 0) * Hd + lane];
        float a1 = wl[(kc + 1) * Hd + lane];
        float a2 = wl[(kc + 2) * Hd + lane];
        float a3 = wl[(kc + 3) * Hd + lane];
        float b0 = wr[(kc + 0) * Hd + lane];
        float b1 = wr[(kc + 1) * Hd + lane];
        float b2 = wr[(kc + 2) * Hd + lane];
        float b3 = wr[(kc + 3) * Hd + lane];
        #pragma unroll
        for (int i = 0; i < 8; i++) {
            const float4 av = *(const float4*)(&lds[wv][i][kc]);
            const float4 hv = *(const float4*)(hin + (size_t)n[i] * Hd + kc);
            acc[i] += av.x * a0 + av.y * a1 + av.z * a2 + av.w * a3
                    + hv.x * b0 + hv.y * b1 + hv.z * b2 + hv.w * b3;
        }
    }
    float bb = bl[d * Hd + lane];
    #pragma unroll
    for (int i = 0; i < 8; i++)
        if (ent[i] >= 0) {
            float v = acc[i] + bb;
            if (relu_out) {
                v = reluf(v);
                hout16[(size_t)n[i] * Hd + lane] = __float2half(v);  // next gather's shadow
            }
            hout[(size_t)n[i] * Hd + lane] = v;
        }
}

// ---- global add pool (batch_idx is sorted -> mostly single fused atomic) ----
__global__ void k_pool(const float* __restrict__ h, const int* __restrict__ batch,
                       float* __restrict__ g) {
    int wave = rfl((blockIdx.x * 256 + threadIdx.x) >> 6);
    int lane = threadIdx.x & 63;
    int n0 = wave * 4;
    if (n0 >= Nn) return;
    int b0 = batch[n0], b1 = batch[n0 + 1], b2 = batch[n0 + 2], b3 = batch[n0 + 3];
    float v0 = h[(size_t)n0 * Hd + lane];
    float v1 = h[(size_t)(n0 + 1) * Hd + lane];
    float v2 = h[(size_t)(n0 + 2) * Hd + lane];
    float v3 = h[(size_t)(n0 + 3) * Hd + lane];
    if (b0 == b1 && b0 == b2 && b0 == b3) {
        unsafeAtomicAdd(&g[(size_t)b0 * Hd + lane], v0 + v1 + v2 + v3);
    } else {
        unsafeAtomicAdd(&g[(size_t)b0 * Hd + lane], v0);
        unsafeAtomicAdd(&g[(size_t)b1 * Hd + lane], v1);
        unsafeAtomicAdd(&g[(size_t)b2 * Hd + lane], v2);
        unsafeAtomicAdd(&g[(size_t)b3 * Hd + lane], v3);
    }
}

// ---- head: relu(g@lin1+b1)@lin2+b2, one wave per graph ----
__global__ void k_head(const float* __restrict__ g, const float* __restrict__ w1,
                       const float* __restrict__ b1, const float* __restrict__ w2,
                       const float* __restrict__ b2, float* __restrict__ out) {
    __shared__ float t[4][Hd];
    int wv = threadIdx.x >> 6;
    int lane = threadIdx.x & 63;
    int gi = blockIdx.x * 4 + wv;
    float acc = b1[lane];
    for (int k = 0; k < Hd; k++) acc += g[(size_t)gi * Hd + k] * w1[k * Hd + lane];
    t[wv][lane] = reluf(acc);
    __syncthreads();
    if (lane < Od) {
        float o = b2[lane];
        for (int k = 0; k < Hd; k++) o += t[wv][k] * w2[k * Od + lane];
        out[(size_t)gi * Od + lane] = o;
    }
}

extern "C" void kernel_launch(void* const* d_in, const int* in_sizes, int n_in,
                              void* d_out, int out_size, void* d_ws, size_t ws_size,
                              hipStream_t stream) {
    const float* x      = (const float*)d_in[0];
    const float* ea     = (const float*)d_in[1];
    const int*   eidx   = (const int*)d_in[2];
    const int*   batch  = (const int*)d_in[3];
    const float* emb    = (const float*)d_in[4];
    const float* lin1_w = (const float*)d_in[5];
    const float* lin1_b = (const float*)d_in[6];
    const float* lin2_w = (const float*)d_in[7];
    const float* lin2_b = (const float*)d_in[8];
    const float* rgcn_w[2]    = {(const float*)d_in[9],  (const float*)d_in[15]};
    const float* rgcn_root[2] = {(const float*)d_in[10], (const float*)d_in[16]};
    const float* rgcn_b[2]    = {(const float*)d_in[11], (const float*)d_in[17]};
    const float* mf_wl[2]     = {(const float*)d_in[12], (const float*)d_in[18]};
    const float* mf_bl[2]     = {(const float*)d_in[13], (const float*)d_in[19]};
    const float* mf_wr[2]     = {(const float*)d_in[14], (const float*)d_in[20]};

    char* p = (char*)d_ws;
    float* h0    = (float*)p; p += sizeof(float) * (size_t)Nn * Hd;
    float* h1    = (float*)p; p += sizeof(float) * (size_t)Nn * Hd;
    __half* h16a = (__half*)p; p += sizeof(__half) * (size_t)Nn * Hd;
    __half* h16b = (__half*)p; p += sizeof(__half) * (size_t)Nn * Hd;
    float* gbuf  = (float*)p; p += sizeof(float) * (size_t)Ng * Hd;
    int* seg     = (int*)p;   p += sizeof(int) * (size_t)Ne;
    int* rank    = (int*)p;   p += sizeof(int) * (size_t)Ne;
    int* ssrc    = (int*)p;   p += sizeof(int) * (size_t)Ne;
    int* cnt     = (int*)p;   p += sizeof(int) * (size_t)NSEG;  // contiguous with bcnt/bfill
    int* bcnt    = (int*)p;   p += sizeof(int) * 16;
    int* bfill   = (int*)p;   p += sizeof(int) * 16;
    int* off     = (int*)p;   p += sizeof(int) * (size_t)(NSEG + 1);
    int* bsum    = (int*)p;   p += sizeof(int) * 1024;
    int* bbase   = (int*)p;   p += sizeof(int) * 16;
    int* order   = (int*)p;   p += sizeof(int) * (size_t)ORDER_SZ;

    hipMemsetAsync(cnt, 0, sizeof(int) * ((size_t)NSEG + 32), stream);
    hipMemsetAsync(gbuf, 0, sizeof(float) * (size_t)Ng * Hd, stream);

    k_rel_emb<<<NB_RELSEG + NB_EMBED, 256, 0, stream>>>((const float4*)ea, eidx, seg, rank,
                                                        cnt, x, emb, h0, h16a);
    k_scan1<<<SCAN_BLK, 256, 0, stream>>>(cnt, off, bsum, bcnt);
    k_scan2<<<1, 1024, 0, stream>>>(bsum, bcnt, bbase, order);
    k_scan3_bucket<<<SCAN_BLK, 256, 0, stream>>>(off, bsum, (const int4*)cnt, bbase,
                                                 bfill, order);
    k_scatter<<<Ne / 256, 256, 0, stream>>>(eidx, seg, rank, off, ssrc);

    float* hin = h0;   __half* hin16 = h16a;
    float* hout = h1;  __half* hout16 = h16b;
    for (int b = 0; b < 2; b++) {
        k_rgcn_fused<<<NB_RG, 256, 0, stream>>>(hin, hin16, off, ssrc, rgcn_w[b],
                                                rgcn_root[b], rgcn_b[b], hout, hout16);
        k_mf_fused<<<NB_MF, 256, 0, stream>>>(hout, hout16, off, ssrc, order, mf_wl[b],
                                              mf_bl[b], mf_wr[b], hin, hin16,
                                              b == 0 ? 1 : 0);
        // block output is back in hin (fp32) + hin16 (shadow, b=0 only; b=1 feeds pool)
    }
    k_pool<<<Nn / 16, 256, 0, stream>>>(hin, batch, gbuf);
    k_head<<<Ng / 4, 256, 0, stream>>>(gbuf, lin1_w, lin1_b, lin2_w, lin2_b, (float*)d_out);
}

// Round 3
// 419.587 us; speedup vs baseline: 1.1288x; 1.1288x over previous
//
#include <hip/hip_runtime.h>
#include <hip/hip_fp16.h>
#include <cstdint>
#include <cstddef>

#define Nn 50000
#define Ne 800000
#define Ng 1024
#define NFd 32
#define Rr 4
#define Hd 64
#define Od 16
#define MAXD 10
#define NSEG (Nn * Rr)
#define SCAN_BLK ((NSEG + 255) / 256)
#define ORDER_SZ (Nn + 48)                 // buckets padded to x4: max 11*3 pad
#define NB_MF ((ORDER_SZ + 15) / 16)       // block = 4 waves x 4 slots
#define NB_RG (Nn / 16)                    // block = 4 waves x 4 nodes
#define NB_RELSEG (Ne / 256)               // 3125 edge blocks
#define NB_EMBED (Nn / 4)                  // 12500 embed blocks

__device__ __forceinline__ float reluf(float v) { return v > 0.f ? v : 0.f; }
__device__ __forceinline__ int rfl(int v) { return __builtin_amdgcn_readfirstlane(v); }

// ---- FUSED: per-edge relation argmax/histogram/rank  +  embedding lookup ----
__global__ void k_rel_emb(const float4* __restrict__ ea, const int* __restrict__ eidx,
                          int* __restrict__ seg, int* __restrict__ rank,
                          int* __restrict__ cnt,
                          const float* __restrict__ x, const float* __restrict__ emb,
                          float* __restrict__ h, __half* __restrict__ h16) {
    if (blockIdx.x < NB_RELSEG) {
        int e = blockIdx.x * 256 + threadIdx.x;     // grid sized exactly: e < Ne
        float4 a = ea[e];
        int bi = 0; float bv = a.x;
        if (a.y > bv) { bv = a.y; bi = 1; }
        if (a.z > bv) { bv = a.z; bi = 2; }
        if (a.w > bv) { bv = a.w; bi = 3; }
        int s = eidx[Ne + e] * Rr + bi;
        seg[e] = s;
        rank[e] = atomicAdd(&cnt[s], 1);
    } else {
        int wave = ((blockIdx.x - NB_RELSEG) * 256 + threadIdx.x) >> 6;  // < Nn
        int lane = threadIdx.x & 63;
        float v = (lane < NFd) ? x[(size_t)wave * NFd + lane] : -1e30f;
        int idx = lane;
        #pragma unroll
        for (int off = 16; off >= 1; off >>= 1) {
            float ov = __shfl_down(v, off);
            int oi = __shfl_down(idx, off);
            if (ov > v || (ov == v && oi < idx)) { v = ov; idx = oi; }
        }
        idx = __shfl(idx, 0);
        float hv = reluf(emb[(size_t)idx * Hd + lane]);
        h[(size_t)wave * Hd + lane] = hv;
        h16[(size_t)wave * Hd + lane] = __float2half(hv);
    }
}

// ---- scan level 1 + fused degree histogram ----
__global__ void k_scan1(const int* __restrict__ cnt, int* __restrict__ off,
                        int* __restrict__ bsum, int* __restrict__ bcnt) {
    __shared__ int s[256];
    __shared__ int hist[16];
    int t = threadIdx.x;
    if (t < 16) hist[t] = 0;
    int idx = blockIdx.x * 256 + t;
    int v = (idx < NSEG) ? cnt[idx] : 0;
    s[t] = v;
    __syncthreads();
    if ((t & 3) == 0 && idx < NSEG) {
        int dsum = s[t] + s[t + 1] + s[t + 2] + s[t + 3];
        atomicAdd(&hist[min(dsum, MAXD)], 1);
    }
    #pragma unroll
    for (int o = 1; o < 256; o <<= 1) {
        int x = (t >= o) ? s[t - o] : 0;
        __syncthreads();
        s[t] += x;
        __syncthreads();
    }
    if (idx < NSEG) off[idx] = s[t] - v;            // exclusive
    if (t == 255) bsum[blockIdx.x] = s[255];
    if (t < 16) {
        int h = hist[t];
        if (h > 0) atomicAdd(&bcnt[t], h);
    }
}

// ---- scan level 2 + fused bucket prefix (4-aligned) + order pad-slot writes ----
__global__ void k_scan2(int* __restrict__ bsum, const int* __restrict__ bcnt,
                        int* __restrict__ bbase, int* __restrict__ order) {
    __shared__ int s[1024];
    int t = threadIdx.x;
    int v = (t < SCAN_BLK) ? bsum[t] : 0;
    s[t] = v;
    __syncthreads();
    #pragma unroll
    for (int o = 1; o < 1024; o <<= 1) {
        int x = (t >= o) ? s[t - o] : 0;
        __syncthreads();
        s[t] += x;
        __syncthreads();
    }
    if (t < SCAN_BLK) bsum[t] = s[t] - v;           // exclusive block bases
    if (t == 0) {
        int run = 0;
        for (int d = 0; d <= MAXD; d++) {
            int c = bcnt[d];
            bbase[d] = run;
            int pad = (c + 3) & ~3;
            for (int i = c; i < pad; i++) order[run + i] = -1;
            run += pad;
        }
        for (int i = run; i < ORDER_SZ; i++) order[i] = -1;
    }
}

// ---- FUSED: scan level 3 (final off)  +  degree-bucket scatter ----
__global__ void k_scan3_bucket(int* __restrict__ off, const int* __restrict__ bsum,
                               const int4* __restrict__ cnt4, const int* __restrict__ bbase,
                               int* __restrict__ bfill, int* __restrict__ order) {
    __shared__ int hist[16];
    __shared__ int base[16];
    int t = threadIdx.x;
    if (t < 16) hist[t] = 0;
    __syncthreads();
    int idx = blockIdx.x * 256 + t;
    if (idx == 0) off[NSEG] = Ne;
    if (idx < NSEG) off[idx] = off[idx] + bsum[blockIdx.x];
    int d = 0, rk = 0;
    bool valid = (idx < Nn);
    if (valid) {
        int4 c = cnt4[idx];
        d = min(c.x + c.y + c.z + c.w, MAXD);
        rk = atomicAdd(&hist[d], 1);
    }
    __syncthreads();
    if (t < 16) {
        int h = hist[t];
        base[t] = (h > 0) ? atomicAdd(&bfill[t], h) : 0;
    }
    __syncthreads();
    if (valid) order[bbase[d] + base[d] + rk] = idx | (d << 20);
}

// ---- scatter edges into segment-sorted order: NO atomics (rank precomputed) ----
__global__ void k_scatter(const int* __restrict__ eidx, const int* __restrict__ seg,
                          const int* __restrict__ rank, const int* __restrict__ off,
                          int* __restrict__ sorted_src) {
    int e = blockIdx.x * 256 + threadIdx.x;
    if (e >= Ne) return;
    int pos = off[seg[e]] + rank[e];
    sorted_src[pos] = eidx[e];
}

#define H16(ptr, s) __half2float((ptr)[(size_t)(s) * Hd + lane])

// ---- FUSED RGCN layer: prefix-snapshot gather (1 add/edge) + in-kernel transform ----
// Wave's 4 nodes = one contiguous 64-edge stream (segment-sorted). Segment sums are
// prefix differences captured at the 16 wave-uniform (node,rel) boundaries -> no
// per-edge relation classification. ssrc int4 loads software-pipelined one chunk ahead.
__global__ __launch_bounds__(256) void k_rgcn_fused(
        const float* __restrict__ hin, const __half* __restrict__ hin16,
        const int* __restrict__ off, const int* __restrict__ ssrc,
        const float* __restrict__ W, const float* __restrict__ Wroot,
        const float* __restrict__ bias, float* __restrict__ hout,
        __half* __restrict__ hout16) {
    __shared__ float lds[4][4][Rr][Hd];             // 16 KB: [wave][node][rel][k]
    int tid = threadIdx.x;
    int wv = tid >> 6, lane = tid & 63;
    int n0 = rfl(blockIdx.x * 16 + wv * 4);
    int ob[17];                                     // wave-uniform segment boundaries
    #pragma unroll
    for (int k = 0; k < 17; k++) ob[k] = rfl(off[4 * n0 + k]);

    float acc = 0.f, snap = 0.f;
    int segi = 0;
    int nb = ob[1];
    int e = ob[0], eEnd = ob[16];

#define EMIT_SEG do {                                                \
        float d_ = acc - snap; snap = acc;                           \
        int cN_ = ob[segi + 1] - ob[segi];                           \
        float iv_ = (cN_ > 0) ? 1.f / (float)cN_ : 0.f;              \
        lds[wv][segi >> 2][segi & 3][lane] = d_ * iv_;               \
        segi++;                                                      \
        nb = (segi < 16) ? ob[segi + 1] : 0x7fffffff;                \
    } while (0)

    if (e + 16 <= eEnd) {
        int4 iA = *(const int4*)(ssrc + e);
        int4 iB = *(const int4*)(ssrc + e + 4);
        int4 iC = *(const int4*)(ssrc + e + 8);
        int4 iD = *(const int4*)(ssrc + e + 12);
        while (true) {
            int en = e + 16;
            bool more = (en + 16 <= eEnd);
            int4 jA, jB, jC, jD;
            if (more) {                             // prefetch next chunk's indices
                jA = *(const int4*)(ssrc + en);
                jB = *(const int4*)(ssrc + en + 4);
                jC = *(const int4*)(ssrc + en + 8);
                jD = *(const int4*)(ssrc + en + 12);
            }
            float v0 = H16(hin16, iA.x);
            float v1 = H16(hin16, iA.y);
            float v2 = H16(hin16, iA.z);
            float v3 = H16(hin16, iA.w);
            float v4 = H16(hin16, iB.x);
            float v5 = H16(hin16, iB.y);
            float v6 = H16(hin16, iB.z);
            float v7 = H16(hin16, iB.w);
            float v8 = H16(hin16, iC.x);
            float v9 = H16(hin16, iC.y);
            float vA = H16(hin16, iC.z);
            float vB = H16(hin16, iC.w);
            float vC = H16(hin16, iD.x);
            float vD = H16(hin16, iD.y);
            float vE = H16(hin16, iD.z);
            float vF = H16(hin16, iD.w);
            // ordered prefix adds; boundary checks are wave-uniform scalar compares
            while (e + 0  == nb) EMIT_SEG;  acc += v0;
            while (e + 1  == nb) EMIT_SEG;  acc += v1;
            while (e + 2  == nb) EMIT_SEG;  acc += v2;
            while (e + 3  == nb) EMIT_SEG;  acc += v3;
            while (e + 4  == nb) EMIT_SEG;  acc += v4;
            while (e + 5  == nb) EMIT_SEG;  acc += v5;
            while (e + 6  == nb) EMIT_SEG;  acc += v6;
            while (e + 7  == nb) EMIT_SEG;  acc += v7;
            while (e + 8  == nb) EMIT_SEG;  acc += v8;
            while (e + 9  == nb) EMIT_SEG;  acc += v9;
            while (e + 10 == nb) EMIT_SEG;  acc += vA;
            while (e + 11 == nb) EMIT_SEG;  acc += vB;
            while (e + 12 == nb) EMIT_SEG;  acc += vC;
            while (e + 13 == nb) EMIT_SEG;  acc += vD;
            while (e + 14 == nb) EMIT_SEG;  acc += vE;
            while (e + 15 == nb) EMIT_SEG;  acc += vF;
            e = en;
            if (!more) break;
            iA = jA; iB = jB; iC = jC; iD = jD;
        }
    }
    for (; e < eEnd; e++) {                         // tail (< 16 edges)
        while (e == nb) EMIT_SEG;
        int s = rfl(ssrc[e]);
        acc += H16(hin16, s);
    }
    while (segi < 16) EMIT_SEG;                     // trailing (possibly empty) segments
#undef EMIT_SEG

    // in-kernel transform: acc[i][j=lane] = hin[n]@Wroot + sum_r a_r@W_r
    float accT[4] = {0.f, 0.f, 0.f, 0.f};
    for (int kc = 0; kc < Hd; kc += 4) {
        float r0 = Wroot[(kc + 0) * Hd + lane];
        float r1 = Wroot[(kc + 1) * Hd + lane];
        float r2 = Wroot[(kc + 2) * Hd + lane];
        float r3 = Wroot[(kc + 3) * Hd + lane];
        float w[4][4];
        #pragma unroll
        for (int rr = 0; rr < 4; rr++) {
            const float* wp = W + ((size_t)rr * Hd + kc) * Hd + lane;
            w[rr][0] = wp[0 * Hd];
            w[rr][1] = wp[1 * Hd];
            w[rr][2] = wp[2 * Hd];
            w[rr][3] = wp[3 * Hd];
        }
        #pragma unroll
        for (int i = 0; i < 4; i++) {
            const float4 hv  = *(const float4*)(hin + (size_t)(n0 + i) * Hd + kc);
            const float4 a0v = *(const float4*)&lds[wv][i][0][kc];
            const float4 a1v = *(const float4*)&lds[wv][i][1][kc];
            const float4 a2v = *(const float4*)&lds[wv][i][2][kc];
            const float4 a3v = *(const float4*)&lds[wv][i][3][kc];
            accT[i] += hv.x * r0 + hv.y * r1 + hv.z * r2 + hv.w * r3
                    + a0v.x * w[0][0] + a0v.y * w[0][1] + a0v.z * w[0][2] + a0v.w * w[0][3]
                    + a1v.x * w[1][0] + a1v.y * w[1][1] + a1v.z * w[1][2] + a1v.w * w[1][3]
                    + a2v.x * w[2][0] + a2v.y * w[2][1] + a2v.z * w[2][2] + a2v.w * w[2][3]
                    + a3v.x * w[3][0] + a3v.y * w[3][1] + a3v.z * w[3][2] + a3v.w * w[3][3];
        }
    }
    float bb = bias[lane];
    #pragma unroll
    for (int i = 0; i < 4; i++) {
        float v = reluf(accT[i] + bb);
        hout[(size_t)(n0 + i) * Hd + lane] = v;
        hout16[(size_t)(n0 + i) * Hd + lane] = __float2half(v);
    }
}

// ---- FUSED MFConv layer: 16-deep fp16 gather + degree-bucketed transform ----
__global__ __launch_bounds__(256) void k_mf_fused(
        const float* __restrict__ hin, const __half* __restrict__ hin16,
        const int* __restrict__ off, const int* __restrict__ ssrc,
        const int* __restrict__ order, const float* __restrict__ Wl,
        const float* __restrict__ bl, const float* __restrict__ Wr,
        float* __restrict__ hout, __half* __restrict__ hout16, int relu_out) {
    __shared__ float lds[4][4][Hd];                 // 4 KB: [wave][node][k]
    int tid = threadIdx.x;
    int wv = tid >> 6, lane = tid & 63;
    int slot0 = rfl(blockIdx.x * 16 + wv * 4);
    int ent[4];
    #pragma unroll
    for (int i = 0; i < 4; i++) ent[i] = rfl(order[slot0 + i]);
    int d = -1;
    #pragma unroll
    for (int i = 3; i >= 0; i--) if (ent[i] >= 0) d = ent[i] >> 20;
    if (d < 0) return;
    int n[4];
    #pragma unroll
    for (int i = 0; i < 4; i++) n[i] = (ent[i] >= 0) ? (ent[i] & 0xFFFFF) : 0;
    for (int i = 0; i < 4; i++) {
        int e0 = rfl(off[n[i] * Rr]);
        int e4 = rfl(off[n[i] * Rr + Rr]);
        float p0 = 0.f, p1 = 0.f, p2 = 0.f, p3 = 0.f;
        int e = e0;
        for (; e + 16 <= e4; e += 16) {
            const int4 sA = *(const int4*)(ssrc + e);
            const int4 sB = *(const int4*)(ssrc + e + 4);
            const int4 sC = *(const int4*)(ssrc + e + 8);
            const int4 sD = *(const int4*)(ssrc + e + 12);
            p0 += H16(hin16, sA.x) + H16(hin16, sA.y) + H16(hin16, sA.z) + H16(hin16, sA.w);
            p1 += H16(hin16, sB.x) + H16(hin16, sB.y) + H16(hin16, sB.z) + H16(hin16, sB.w);
            p2 += H16(hin16, sC.x) + H16(hin16, sC.y) + H16(hin16, sC.z) + H16(hin16, sC.w);
            p3 += H16(hin16, sD.x) + H16(hin16, sD.y) + H16(hin16, sD.z) + H16(hin16, sD.w);
        }
        for (; e + 4 <= e4; e += 4) {
            const int4 sA = *(const int4*)(ssrc + e);
            p0 += H16(hin16, sA.x) + H16(hin16, sA.y) + H16(hin16, sA.z) + H16(hin16, sA.w);
        }
        for (; e < e4; e++) {
            int s = rfl(ssrc[e]);
            p0 += H16(hin16, s);
        }
        lds[wv][i][lane] = (p0 + p1) + (p2 + p3);
    }
    const float* wl = Wl + (size_t)d * Hd * Hd;
    const float* wr = Wr + (size_t)d * Hd * Hd;
    float acc[4] = {0.f, 0.f, 0.f, 0.f};
    for (int kc = 0; kc < Hd; kc += 4) {
        float a0 = wl[(kc + 0) * Hd + lane];
        float a1 = wl[(kc + 1) * Hd + lane];
        float a2 = wl[(kc + 2) * Hd + lane];
        float a3 = wl[(kc + 3) * Hd + lane];
        float b0 = wr[(kc + 0) * Hd + lane];
        float b1 = wr[(kc + 1) * Hd + lane];
        float b2 = wr[(kc + 2) * Hd + lane];
        float b3 = wr[(kc + 3) * Hd + lane];
        #pragma unroll
        for (int i = 0; i < 4; i++) {
            const float4 av = *(const float4*)(&lds[wv][i][kc]);
            const float4 hv = *(const float4*)(hin + (size_t)n[i] * Hd + kc);
            acc[i] += av.x * a0 + av.y * a1 + av.z * a2 + av.w * a3
                    + hv.x * b0 + hv.y * b1 + hv.z * b2 + hv.w * b3;
        }
    }
    float bb = bl[d * Hd + lane];
    #pragma unroll
    for (int i = 0; i < 4; i++)
        if (ent[i] >= 0) {
            float v = acc[i] + bb;
            if (relu_out) {
                v = reluf(v);
                hout16[(size_t)n[i] * Hd + lane] = __float2half(v);  // next gather's shadow
            }
            hout[(size_t)n[i] * Hd + lane] = v;
        }
}

// ---- global add pool (batch_idx is sorted -> mostly single fused atomic) ----
__global__ void k_pool(const float* __restrict__ h, const int* __restrict__ batch,
                       float* __restrict__ g) {
    int wave = rfl((blockIdx.x * 256 + threadIdx.x) >> 6);
    int lane = threadIdx.x & 63;
    int n0 = wave * 4;
    if (n0 >= Nn) return;
    int b0 = batch[n0], b1 = batch[n0 + 1], b2 = batch[n0 + 2], b3 = batch[n0 + 3];
    float v0 = h[(size_t)n0 * Hd + lane];
    float v1 = h[(size_t)(n0 + 1) * Hd + lane];
    float v2 = h[(size_t)(n0 + 2) * Hd + lane];
    float v3 = h[(size_t)(n0 + 3) * Hd + lane];
    if (b0 == b1 && b0 == b2 && b0 == b3) {
        unsafeAtomicAdd(&g[(size_t)b0 * Hd + lane], v0 + v1 + v2 + v3);
    } else {
        unsafeAtomicAdd(&g[(size_t)b0 * Hd + lane], v0);
        unsafeAtomicAdd(&g[(size_t)b1 * Hd + lane], v1);
        unsafeAtomicAdd(&g[(size_t)b2 * Hd + lane], v2);
        unsafeAtomicAdd(&g[(size_t)b3 * Hd + lane], v3);
    }
}

// ---- head: relu(g@lin1+b1)@lin2+b2, one wave per graph ----
__global__ void k_head(const float* __restrict__ g, const float* __restrict__ w1,
                       const float* __restrict__ b1, const float* __restrict__ w2,
                       const float* __restrict__ b2, float* __restrict__ out) {
    __shared__ float t[4][Hd];
    int wv = threadIdx.x >> 6;
    int lane = threadIdx.x & 63;
    int gi = blockIdx.x * 4 + wv;
    float acc = b1[lane];
    for (int k = 0; k < Hd; k++) acc += g[(size_t)gi * Hd + k] * w1[k * Hd + lane];
    t[wv][lane] = reluf(acc);
    __syncthreads();
    if (lane < Od) {
        float o = b2[lane];
        for (int k = 0; k < Hd; k++) o += t[wv][k] * w2[k * Od + lane];
        out[(size_t)gi * Od + lane] = o;
    }
}

extern "C" void kernel_launch(void* const* d_in, const int* in_sizes, int n_in,
                              void* d_out, int out_size, void* d_ws, size_t ws_size,
                              hipStream_t stream) {
    const float* x      = (const float*)d_in[0];
    const float* ea     = (const float*)d_in[1];
    const int*   eidx   = (const int*)d_in[2];
    const int*   batch  = (const int*)d_in[3];
    const float* emb    = (const float*)d_in[4];
    const float* lin1_w = (const float*)d_in[5];
    const float* lin1_b = (const float*)d_in[6];
    const float* lin2_w = (const float*)d_in[7];
    const float* lin2_b = (const float*)d_in[8];
    const float* rgcn_w[2]    = {(const float*)d_in[9],  (const float*)d_in[15]};
    const float* rgcn_root[2] = {(const float*)d_in[10], (const float*)d_in[16]};
    const float* rgcn_b[2]    = {(const float*)d_in[11], (const float*)d_in[17]};
    const float* mf_wl[2]     = {(const float*)d_in[12], (const float*)d_in[18]};
    const float* mf_bl[2]     = {(const float*)d_in[13], (const float*)d_in[19]};
    const float* mf_wr[2]     = {(const float*)d_in[14], (const float*)d_in[20]};

    char* p = (char*)d_ws;
    float* h0    = (float*)p; p += sizeof(float) * (size_t)Nn * Hd;
    float* h1    = (float*)p; p += sizeof(float) * (size_t)Nn * Hd;
    __half* h16a = (__half*)p; p += sizeof(__half) * (size_t)Nn * Hd;
    __half* h16b = (__half*)p; p += sizeof(__half) * (size_t)Nn * Hd;
    float* gbuf  = (float*)p; p += sizeof(float) * (size_t)Ng * Hd;
    int* seg     = (int*)p;   p += sizeof(int) * (size_t)Ne;
    int* rank    = (int*)p;   p += sizeof(int) * (size_t)Ne;
    int* ssrc    = (int*)p;   p += sizeof(int) * (size_t)Ne;
    int* cnt     = (int*)p;   p += sizeof(int) * (size_t)NSEG;  // contiguous with bcnt/bfill
    int* bcnt    = (int*)p;   p += sizeof(int) * 16;
    int* bfill   = (int*)p;   p += sizeof(int) * 16;
    int* off     = (int*)p;   p += sizeof(int) * (size_t)(NSEG + 1);
    int* bsum    = (int*)p;   p += sizeof(int) * 1024;
    int* bbase   = (int*)p;   p += sizeof(int) * 16;
    int* order   = (int*)p;   p += sizeof(int) * (size_t)ORDER_SZ;

    hipMemsetAsync(cnt, 0, sizeof(int) * ((size_t)NSEG + 32), stream);
    hipMemsetAsync(gbuf, 0, sizeof(float) * (size_t)Ng * Hd, stream);

    k_rel_emb<<<NB_RELSEG + NB_EMBED, 256, 0, stream>>>((const float4*)ea, eidx, seg, rank,
                                                        cnt, x, emb, h0, h16a);
    k_scan1<<<SCAN_BLK, 256, 0, stream>>>(cnt, off, bsum, bcnt);
    k_scan2<<<1, 1024, 0, stream>>>(bsum, bcnt, bbase, order);
    k_scan3_bucket<<<SCAN_BLK, 256, 0, stream>>>(off, bsum, (const int4*)cnt, bbase,
                                                 bfill, order);
    k_scatter<<<Ne / 256, 256, 0, stream>>>(eidx, seg, rank, off, ssrc);

    float* hin = h0;   __half* hin16 = h16a;
    float* hout = h1;  __half* hout16 = h16b;
    for (int b = 0; b < 2; b++) {
        k_rgcn_fused<<<NB_RG, 256, 0, stream>>>(hin, hin16, off, ssrc, rgcn_w[b],
                                                rgcn_root[b], rgcn_b[b], hout, hout16);
        k_mf_fused<<<NB_MF, 256, 0, stream>>>(hout, hout16, off, ssrc, order, mf_wl[b],
                                              mf_bl[b], mf_wr[b], hin, hin16,
                                              b == 0 ? 1 : 0);
        // block output is back in hin (fp32) + hin16 (shadow, b=0 only; b=1 feeds pool)
    }
    k_pool<<<Nn / 16, 256, 0, stream>>>(hin, batch, gbuf);
    k_head<<<Ng / 4, 256, 0, stream>>>(gbuf, lin1_w, lin1_b, lin2_w, lin2_b, (float*)d_out);
}

// Round 4
// 362.996 us; speedup vs baseline: 1.3048x; 1.1559x over previous
//
#include <hip/hip_runtime.h>
#include <hip/hip_fp16.h>
#include <cstdint>
#include <cstddef>

#define Nn 50000
#define Ne 800000
#define Ng 1024
#define NFd 32
#define Rr 4
#define Hd 64
#define Od 16
#define MAXD 10
#define NSEG (Nn * Rr)
#define SCAN_BLK ((NSEG + 255) / 256)
#define ORDER_SZ (Nn + 48)                 // buckets padded to x4: max 11*3 pad
#define NB_MF ((ORDER_SZ + 15) / 16)       // block = 4 waves x 4 slots
#define NB_RG (Nn / 16)                    // block = 4 waves; 16 nodes/block (MFMA tile)
#define NB_RELSEG (Ne / 256)               // 3125 edge blocks
#define NB_EMBED (Nn / 4)                  // 12500 embed blocks
#define WT_PER_LAYER (Hd * 5 * Hd)         // 20480 halves: [64 cols][320 k]

typedef _Float16 f16x8 __attribute__((ext_vector_type(8)));
typedef float f32x4 __attribute__((ext_vector_type(4)));

__device__ __forceinline__ float reluf(float v) { return v > 0.f ? v : 0.f; }
__device__ __forceinline__ int rfl(int v) { return __builtin_amdgcn_readfirstlane(v); }

// ---- FUSED: per-edge relation argmax/histogram/rank  +  embedding lookup ----
__global__ void k_rel_emb(const float4* __restrict__ ea, const int* __restrict__ eidx,
                          int* __restrict__ seg, int* __restrict__ rank,
                          int* __restrict__ cnt,
                          const float* __restrict__ x, const float* __restrict__ emb,
                          float* __restrict__ h, __half* __restrict__ h16) {
    if (blockIdx.x < NB_RELSEG) {
        int e = blockIdx.x * 256 + threadIdx.x;     // grid sized exactly: e < Ne
        float4 a = ea[e];
        int bi = 0; float bv = a.x;
        if (a.y > bv) { bv = a.y; bi = 1; }
        if (a.z > bv) { bv = a.z; bi = 2; }
        if (a.w > bv) { bv = a.w; bi = 3; }
        int s = eidx[Ne + e] * Rr + bi;
        seg[e] = s;
        rank[e] = atomicAdd(&cnt[s], 1);
    } else {
        int wave = ((blockIdx.x - NB_RELSEG) * 256 + threadIdx.x) >> 6;  // < Nn
        int lane = threadIdx.x & 63;
        float v = (lane < NFd) ? x[(size_t)wave * NFd + lane] : -1e30f;
        int idx = lane;
        #pragma unroll
        for (int off = 16; off >= 1; off >>= 1) {
            float ov = __shfl_down(v, off);
            int oi = __shfl_down(idx, off);
            if (ov > v || (ov == v && oi < idx)) { v = ov; idx = oi; }
        }
        idx = __shfl(idx, 0);
        float hv = reluf(emb[(size_t)idx * Hd + lane]);
        h[(size_t)wave * Hd + lane] = hv;
        h16[(size_t)wave * Hd + lane] = __float2half(hv);
    }
}

// ---- prep: fp16 transposed-stacked RGCN weights Wt16[layer][c][320] ----
// k<64 -> Wroot[k][c]; k=64+64r+kk -> W[r][kk][c]. B-fragment reads become
// single contiguous 16B loads in the MFMA transform.
__global__ void k_prep_wt(const float* __restrict__ w0, const float* __restrict__ r0,
                          const float* __restrict__ w1, const float* __restrict__ r1,
                          __half* __restrict__ wt) {
    int idx = blockIdx.x * 256 + threadIdx.x;
    if (idx >= 2 * WT_PER_LAYER) return;
    int b = idx / WT_PER_LAYER;
    int rem = idx % WT_PER_LAYER;
    int c = rem / 320;
    int k = rem % 320;
    const float* W  = b ? w1 : w0;
    const float* Rt = b ? r1 : r0;
    float v = (k < 64) ? Rt[k * Hd + c]
                       : W[((size_t)((k - 64) >> 6)) * Hd * Hd + ((k - 64) & 63) * Hd + c];
    wt[idx] = __float2half(v);
}

// ---- scan level 1 + fused degree histogram ----
__global__ void k_scan1(const int* __restrict__ cnt, int* __restrict__ off,
                        int* __restrict__ bsum, int* __restrict__ bcnt) {
    __shared__ int s[256];
    __shared__ int hist[16];
    int t = threadIdx.x;
    if (t < 16) hist[t] = 0;
    int idx = blockIdx.x * 256 + t;
    int v = (idx < NSEG) ? cnt[idx] : 0;
    s[t] = v;
    __syncthreads();
    if ((t & 3) == 0 && idx < NSEG) {
        int dsum = s[t] + s[t + 1] + s[t + 2] + s[t + 3];
        atomicAdd(&hist[min(dsum, MAXD)], 1);
    }
    #pragma unroll
    for (int o = 1; o < 256; o <<= 1) {
        int x = (t >= o) ? s[t - o] : 0;
        __syncthreads();
        s[t] += x;
        __syncthreads();
    }
    if (idx < NSEG) off[idx] = s[t] - v;            // exclusive
    if (t == 255) bsum[blockIdx.x] = s[255];
    if (t < 16) {
        int h = hist[t];
        if (h > 0) atomicAdd(&bcnt[t], h);
    }
}

// ---- scan level 2 + fused bucket prefix (4-aligned) + order pad-slot writes ----
__global__ void k_scan2(int* __restrict__ bsum, const int* __restrict__ bcnt,
                        int* __restrict__ bbase, int* __restrict__ order) {
    __shared__ int s[1024];
    int t = threadIdx.x;
    int v = (t < SCAN_BLK) ? bsum[t] : 0;
    s[t] = v;
    __syncthreads();
    #pragma unroll
    for (int o = 1; o < 1024; o <<= 1) {
        int x = (t >= o) ? s[t - o] : 0;
        __syncthreads();
        s[t] += x;
        __syncthreads();
    }
    if (t < SCAN_BLK) bsum[t] = s[t] - v;           // exclusive block bases
    if (t == 0) {
        int run = 0;
        for (int d = 0; d <= MAXD; d++) {
            int c = bcnt[d];
            bbase[d] = run;
            int pad = (c + 3) & ~3;
            for (int i = c; i < pad; i++) order[run + i] = -1;
            run += pad;
        }
        for (int i = run; i < ORDER_SZ; i++) order[i] = -1;
    }
}

// ---- FUSED: scan level 3 (final off)  +  degree-bucket scatter ----
__global__ void k_scan3_bucket(int* __restrict__ off, const int* __restrict__ bsum,
                               const int4* __restrict__ cnt4, const int* __restrict__ bbase,
                               int* __restrict__ bfill, int* __restrict__ order) {
    __shared__ int hist[16];
    __shared__ int base[16];
    int t = threadIdx.x;
    if (t < 16) hist[t] = 0;
    __syncthreads();
    int idx = blockIdx.x * 256 + t;
    if (idx == 0) off[NSEG] = Ne;
    if (idx < NSEG) off[idx] = off[idx] + bsum[blockIdx.x];
    int d = 0, rk = 0;
    bool valid = (idx < Nn);
    if (valid) {
        int4 c = cnt4[idx];
        d = min(c.x + c.y + c.z + c.w, MAXD);
        rk = atomicAdd(&hist[d], 1);
    }
    __syncthreads();
    if (t < 16) {
        int h = hist[t];
        base[t] = (h > 0) ? atomicAdd(&bfill[t], h) : 0;
    }
    __syncthreads();
    if (valid) order[bbase[d] + base[d] + rk] = idx | (d << 20);
}

// ---- scatter edges into segment-sorted order: NO atomics (rank precomputed) ----
__global__ void k_scatter(const int* __restrict__ eidx, const int* __restrict__ seg,
                          const int* __restrict__ rank, const int* __restrict__ off,
                          int* __restrict__ sorted_src) {
    int e = blockIdx.x * 256 + threadIdx.x;
    if (e >= Ne) return;
    int pos = off[seg[e]] + rank[e];
    sorted_src[pos] = eidx[e];
}

#define H16(ptr, s) __half2float((ptr)[(size_t)(s) * Hd + lane])

// ---- FUSED RGCN layer: prefix-snapshot gather -> fp16 LDS -> MFMA transform ----
// Block = 16 nodes. Phase 1: each wave gathers 4 nodes' relation means (fp16 LDS,
// strides padded for 2-way-max bank conflicts). Phase 2 (after one barrier): each
// wave computes a 16x16 output tile = [16 x 320] @ [320 x 16-col-slice] via
// 10x mfma_f32_16x16x32_f16 (A: hin16 global + agg LDS; B: prepped Wt16, L2-hot).
__global__ __launch_bounds__(256) void k_rgcn_fused(
        const __half* __restrict__ hin16,
        const int* __restrict__ off, const int* __restrict__ ssrc,
        const __half* __restrict__ wt, const float* __restrict__ bias,
        float* __restrict__ hout, __half* __restrict__ hout16) {
    __shared__ __align__(16) __half alds[16 * 296];  // [node]: rel*72 + k; node stride 296
    int tid = threadIdx.x;
    int wv = tid >> 6, lane = tid & 63;
    int nblk = rfl(blockIdx.x * 16);
    int n0 = nblk + wv * 4;
    int ob[17];                                     // wave-uniform segment boundaries
    #pragma unroll
    for (int k = 0; k < 17; k++) ob[k] = rfl(off[4 * n0 + k]);

    float acc = 0.f, snap = 0.f;
    int segi = 0;
    int nb = ob[1];
    int e = ob[0], eEnd = ob[16];

#define EMIT_SEG do {                                                \
        float d_ = acc - snap; snap = acc;                           \
        int cN_ = ob[segi + 1] - ob[segi];                           \
        float iv_ = (cN_ > 0) ? 1.f / (float)cN_ : 0.f;              \
        alds[(wv * 4 + (segi >> 2)) * 296 + (segi & 3) * 72 + lane]  \
            = __float2half(d_ * iv_);                                \
        segi++;                                                      \
        nb = (segi < 16) ? ob[segi + 1] : 0x7fffffff;                \
    } while (0)

    if (e + 16 <= eEnd) {
        int4 iA = *(const int4*)(ssrc + e);
        int4 iB = *(const int4*)(ssrc + e + 4);
        int4 iC = *(const int4*)(ssrc + e + 8);
        int4 iD = *(const int4*)(ssrc + e + 12);
        while (true) {
            int en = e + 16;
            bool more = (en + 16 <= eEnd);
            int4 jA, jB, jC, jD;
            if (more) {                             // prefetch next chunk's indices
                jA = *(const int4*)(ssrc + en);
                jB = *(const int4*)(ssrc + en + 4);
                jC = *(const int4*)(ssrc + en + 8);
                jD = *(const int4*)(ssrc + en + 12);
            }
            float v0 = H16(hin16, iA.x);
            float v1 = H16(hin16, iA.y);
            float v2 = H16(hin16, iA.z);
            float v3 = H16(hin16, iA.w);
            float v4 = H16(hin16, iB.x);
            float v5 = H16(hin16, iB.y);
            float v6 = H16(hin16, iB.z);
            float v7 = H16(hin16, iB.w);
            float v8 = H16(hin16, iC.x);
            float v9 = H16(hin16, iC.y);
            float vA = H16(hin16, iC.z);
            float vB = H16(hin16, iC.w);
            float vC = H16(hin16, iD.x);
            float vD = H16(hin16, iD.y);
            float vE = H16(hin16, iD.z);
            float vF = H16(hin16, iD.w);
            // ordered prefix adds; boundary checks are wave-uniform scalar compares
            while (e + 0  == nb) EMIT_SEG;  acc += v0;
            while (e + 1  == nb) EMIT_SEG;  acc += v1;
            while (e + 2  == nb) EMIT_SEG;  acc += v2;
            while (e + 3  == nb) EMIT_SEG;  acc += v3;
            while (e + 4  == nb) EMIT_SEG;  acc += v4;
            while (e + 5  == nb) EMIT_SEG;  acc += v5;
            while (e + 6  == nb) EMIT_SEG;  acc += v6;
            while (e + 7  == nb) EMIT_SEG;  acc += v7;
            while (e + 8  == nb) EMIT_SEG;  acc += v8;
            while (e + 9  == nb) EMIT_SEG;  acc += v9;
            while (e + 10 == nb) EMIT_SEG;  acc += vA;
            while (e + 11 == nb) EMIT_SEG;  acc += vB;
            while (e + 12 == nb) EMIT_SEG;  acc += vC;
            while (e + 13 == nb) EMIT_SEG;  acc += vD;
            while (e + 14 == nb) EMIT_SEG;  acc += vE;
            while (e + 15 == nb) EMIT_SEG;  acc += vF;
            e = en;
            if (!more) break;
            iA = jA; iB = jB; iC = jC; iD = jD;
        }
    }
    for (; e < eEnd; e++) {                         // tail (< 16 edges)
        while (e == nb) EMIT_SEG;
        int s = rfl(ssrc[e]);
        acc += H16(hin16, s);
    }
    while (segi < 16) EMIT_SEG;                     // trailing (possibly empty) segments
#undef EMIT_SEG

    __syncthreads();                                // waves share the A tile now

    // ---- MFMA transform: wave wv -> output cols [16wv, 16wv+16), 16 nodes ----
    // frag mapping: A row / B col = lane&15; k = 8*(lane>>4)+j (m92/m97 pattern);
    // C/D: col = lane&15, row = 4*(lane>>4)+reg (m89-verified).
    int rp = lane & 15;
    int g  = lane >> 4;
    const __half* ha = hin16 + (size_t)(nblk + rp) * Hd + 8 * g;
    const __half* ba = wt + (size_t)(wv * 16 + rp) * 320 + 8 * g;
    const __half* aa = alds + rp * 296 + 8 * g;
    f32x4 dacc = {0.f, 0.f, 0.f, 0.f};
    #pragma unroll
    for (int s = 0; s < 10; s++) {                  // k0 = 32*s; a-source matches (32s)
        f16x8 bfrag = *(const f16x8*)(ba + s * 32);
        f16x8 afrag;
        if (s < 2) afrag = *(const f16x8*)(ha + s * 32);
        else       afrag = *(const f16x8*)(aa + ((s - 2) >> 1) * 72 + ((s - 2) & 1) * 32);
        dacc = __builtin_amdgcn_mfma_f32_16x16x32_f16(afrag, bfrag, dacc, 0, 0, 0);
    }
    int c = wv * 16 + rp;
    float bb = bias[c];
    #pragma unroll
    for (int j = 0; j < 4; j++) {
        int row = nblk + g * 4 + j;
        float v = reluf(dacc[j] + bb);
        hout[(size_t)row * Hd + c] = v;
        hout16[(size_t)row * Hd + c] = __float2half(v);
    }
}

// ---- FUSED MFConv layer: 16-deep fp16 gather + degree-bucketed transform ----
__global__ __launch_bounds__(256) void k_mf_fused(
        const float* __restrict__ hin, const __half* __restrict__ hin16,
        const int* __restrict__ off, const int* __restrict__ ssrc,
        const int* __restrict__ order, const float* __restrict__ Wl,
        const float* __restrict__ bl, const float* __restrict__ Wr,
        float* __restrict__ hout, __half* __restrict__ hout16, int relu_out) {
    __shared__ float lds[4][4][Hd];                 // 4 KB: [wave][node][k]
    int tid = threadIdx.x;
    int wv = tid >> 6, lane = tid & 63;
    int slot0 = rfl(blockIdx.x * 16 + wv * 4);
    int ent[4];
    #pragma unroll
    for (int i = 0; i < 4; i++) ent[i] = rfl(order[slot0 + i]);
    int d = -1;
    #pragma unroll
    for (int i = 3; i >= 0; i--) if (ent[i] >= 0) d = ent[i] >> 20;
    if (d < 0) return;
    int n[4];
    #pragma unroll
    for (int i = 0; i < 4; i++) n[i] = (ent[i] >= 0) ? (ent[i] & 0xFFFFF) : 0;
    for (int i = 0; i < 4; i++) {
        int e0 = rfl(off[n[i] * Rr]);
        int e4 = rfl(off[n[i] * Rr + Rr]);
        float p0 = 0.f, p1 = 0.f, p2 = 0.f, p3 = 0.f;
        int e = e0;
        for (; e + 16 <= e4; e += 16) {
            const int4 sA = *(const int4*)(ssrc + e);
            const int4 sB = *(const int4*)(ssrc + e + 4);
            const int4 sC = *(const int4*)(ssrc + e + 8);
            const int4 sD = *(const int4*)(ssrc + e + 12);
            p0 += H16(hin16, sA.x) + H16(hin16, sA.y) + H16(hin16, sA.z) + H16(hin16, sA.w);
            p1 += H16(hin16, sB.x) + H16(hin16, sB.y) + H16(hin16, sB.z) + H16(hin16, sB.w);
            p2 += H16(hin16, sC.x) + H16(hin16, sC.y) + H16(hin16, sC.z) + H16(hin16, sC.w);
            p3 += H16(hin16, sD.x) + H16(hin16, sD.y) + H16(hin16, sD.z) + H16(hin16, sD.w);
        }
        for (; e + 4 <= e4; e += 4) {
            const int4 sA = *(const int4*)(ssrc + e);
            p0 += H16(hin16, sA.x) + H16(hin16, sA.y) + H16(hin16, sA.z) + H16(hin16, sA.w);
        }
        for (; e < e4; e++) {
            int s = rfl(ssrc[e]);
            p0 += H16(hin16, s);
        }
        lds[wv][i][lane] = (p0 + p1) + (p2 + p3);
    }
    const float* wl = Wl + (size_t)d * Hd * Hd;
    const float* wr = Wr + (size_t)d * Hd * Hd;
    float acc[4] = {0.f, 0.f, 0.f, 0.f};
    for (int kc = 0; kc < Hd; kc += 4) {
        float a0 = wl[(kc + 0) * Hd + lane];
        float a1 = wl[(kc + 1) * Hd + lane];
        float a2 = wl[(kc + 2) * Hd + lane];
        float a3 = wl[(kc + 3) * Hd + lane];
        float b0 = wr[(kc + 0) * Hd + lane];
        float b1 = wr[(kc + 1) * Hd + lane];
        float b2 = wr[(kc + 2) * Hd + lane];
        float b3 = wr[(kc + 3) * Hd + lane];
        #pragma unroll
        for (int i = 0; i < 4; i++) {
            const float4 av = *(const float4*)(&lds[wv][i][kc]);
            const float4 hv = *(const float4*)(hin + (size_t)n[i] * Hd + kc);
            acc[i] += av.x * a0 + av.y * a1 + av.z * a2 + av.w * a3
                    + hv.x * b0 + hv.y * b1 + hv.z * b2 + hv.w * b3;
        }
    }
    float bb = bl[d * Hd + lane];
    #pragma unroll
    for (int i = 0; i < 4; i++)
        if (ent[i] >= 0) {
            float v = acc[i] + bb;
            if (relu_out) {
                v = reluf(v);
                hout16[(size_t)n[i] * Hd + lane] = __float2half(v);  // next gather's shadow
            }
            hout[(size_t)n[i] * Hd + lane] = v;
        }
}

// ---- global add pool (batch_idx is sorted -> mostly single fused atomic) ----
__global__ void k_pool(const float* __restrict__ h, const int* __restrict__ batch,
                       float* __restrict__ g) {
    int wave = rfl((blockIdx.x * 256 + threadIdx.x) >> 6);
    int lane = threadIdx.x & 63;
    int n0 = wave * 4;
    if (n0 >= Nn) return;
    int b0 = batch[n0], b1 = batch[n0 + 1], b2 = batch[n0 + 2], b3 = batch[n0 + 3];
    float v0 = h[(size_t)n0 * Hd + lane];
    float v1 = h[(size_t)(n0 + 1) * Hd + lane];
    float v2 = h[(size_t)(n0 + 2) * Hd + lane];
    float v3 = h[(size_t)(n0 + 3) * Hd + lane];
    if (b0 == b1 && b0 == b2 && b0 == b3) {
        unsafeAtomicAdd(&g[(size_t)b0 * Hd + lane], v0 + v1 + v2 + v3);
    } else {
        unsafeAtomicAdd(&g[(size_t)b0 * Hd + lane], v0);
        unsafeAtomicAdd(&g[(size_t)b1 * Hd + lane], v1);
        unsafeAtomicAdd(&g[(size_t)b2 * Hd + lane], v2);
        unsafeAtomicAdd(&g[(size_t)b3 * Hd + lane], v3);
    }
}

// ---- head: relu(g@lin1+b1)@lin2+b2, one wave per graph ----
__global__ void k_head(const float* __restrict__ g, const float* __restrict__ w1,
                       const float* __restrict__ b1, const float* __restrict__ w2,
                       const float* __restrict__ b2, float* __restrict__ out) {
    __shared__ float t[4][Hd];
    int wv = threadIdx.x >> 6;
    int lane = threadIdx.x & 63;
    int gi = blockIdx.x * 4 + wv;
    float acc = b1[lane];
    for (int k = 0; k < Hd; k++) acc += g[(size_t)gi * Hd + k] * w1[k * Hd + lane];
    t[wv][lane] = reluf(acc);
    __syncthreads();
    if (lane < Od) {
        float o = b2[lane];
        for (int k = 0; k < Hd; k++) o += t[wv][k] * w2[k * Od + lane];
        out[(size_t)gi * Od + lane] = o;
    }
}

extern "C" void kernel_launch(void* const* d_in, const int* in_sizes, int n_in,
                              void* d_out, int out_size, void* d_ws, size_t ws_size,
                              hipStream_t stream) {
    const float* x      = (const float*)d_in[0];
    const float* ea     = (const float*)d_in[1];
    const int*   eidx   = (const int*)d_in[2];
    const int*   batch  = (const int*)d_in[3];
    const float* emb    = (const float*)d_in[4];
    const float* lin1_w = (const float*)d_in[5];
    const float* lin1_b = (const float*)d_in[6];
    const float* lin2_w = (const float*)d_in[7];
    const float* lin2_b = (const float*)d_in[8];
    const float* rgcn_w[2]    = {(const float*)d_in[9],  (const float*)d_in[15]};
    const float* rgcn_root[2] = {(const float*)d_in[10], (const float*)d_in[16]};
    const float* rgcn_b[2]    = {(const float*)d_in[11], (const float*)d_in[17]};
    const float* mf_wl[2]     = {(const float*)d_in[12], (const float*)d_in[18]};
    const float* mf_bl[2]     = {(const float*)d_in[13], (const float*)d_in[19]};
    const float* mf_wr[2]     = {(const float*)d_in[14], (const float*)d_in[20]};

    char* p = (char*)d_ws;
    float* h0    = (float*)p; p += sizeof(float) * (size_t)Nn * Hd;
    float* h1    = (float*)p; p += sizeof(float) * (size_t)Nn * Hd;
    __half* h16a = (__half*)p; p += sizeof(__half) * (size_t)Nn * Hd;
    __half* h16b = (__half*)p; p += sizeof(__half) * (size_t)Nn * Hd;
    float* gbuf  = (float*)p; p += sizeof(float) * (size_t)Ng * Hd;
    __half* wt16 = (__half*)p; p += sizeof(__half) * (size_t)2 * WT_PER_LAYER;
    int* seg     = (int*)p;   p += sizeof(int) * (size_t)Ne;
    int* rank    = (int*)p;   p += sizeof(int) * (size_t)Ne;
    int* ssrc    = (int*)p;   p += sizeof(int) * (size_t)Ne;
    int* cnt     = (int*)p;   p += sizeof(int) * (size_t)NSEG;  // contiguous with bcnt/bfill
    int* bcnt    = (int*)p;   p += sizeof(int) * 16;
    int* bfill   = (int*)p;   p += sizeof(int) * 16;
    int* off     = (int*)p;   p += sizeof(int) * (size_t)(NSEG + 1);
    int* bsum    = (int*)p;   p += sizeof(int) * 1024;
    int* bbase   = (int*)p;   p += sizeof(int) * 16;
    int* order   = (int*)p;   p += sizeof(int) * (size_t)ORDER_SZ;

    hipMemsetAsync(cnt, 0, sizeof(int) * ((size_t)NSEG + 32), stream);
    hipMemsetAsync(gbuf, 0, sizeof(float) * (size_t)Ng * Hd, stream);

    k_prep_wt<<<(2 * WT_PER_LAYER + 255) / 256, 256, 0, stream>>>(
        rgcn_w[0], rgcn_root[0], rgcn_w[1], rgcn_root[1], wt16);
    k_rel_emb<<<NB_RELSEG + NB_EMBED, 256, 0, stream>>>((const float4*)ea, eidx, seg, rank,
                                                        cnt, x, emb, h0, h16a);
    k_scan1<<<SCAN_BLK, 256, 0, stream>>>(cnt, off, bsum, bcnt);
    k_scan2<<<1, 1024, 0, stream>>>(bsum, bcnt, bbase, order);
    k_scan3_bucket<<<SCAN_BLK, 256, 0, stream>>>(off, bsum, (const int4*)cnt, bbase,
                                                 bfill, order);
    k_scatter<<<Ne / 256, 256, 0, stream>>>(eidx, seg, rank, off, ssrc);

    float* hin = h0;   __half* hin16 = h16a;
    float* hout = h1;  __half* hout16 = h16b;
    for (int b = 0; b < 2; b++) {
        k_rgcn_fused<<<NB_RG, 256, 0, stream>>>(hin16, off, ssrc, wt16 + b * WT_PER_LAYER,
                                                rgcn_b[b], hout, hout16);
        k_mf_fused<<<NB_MF, 256, 0, stream>>>(hout, hout16, off, ssrc, order, mf_wl[b],
                                              mf_bl[b], mf_wr[b], hin, hin16,
                                              b == 0 ? 1 : 0);
        // block output is back in hin (fp32) + hin16 (shadow, b=0 only; b=1 feeds pool)
    }
    k_pool<<<Nn / 16, 256, 0, stream>>>(hin, batch, gbuf);
    k_head<<<Ng / 4, 256, 0, stream>>>(gbuf, lin1_w, lin1_b, lin2_w, lin2_b, (float*)d_out);
}

// Round 5
// 356.017 us; speedup vs baseline: 1.3304x; 1.0196x over previous
//
#include <hip/hip_runtime.h>
#include <hip/hip_fp16.h>
#include <cstdint>
#include <cstddef>

#define Nn 50000
#define Ne 800000
#define Ng 1024
#define NFd 32
#define Rr 4
#define Hd 64
#define Od 16
#define MAXD 10
#define NSEG (Nn * Rr)
#define SCAN_BLK ((NSEG + 255) / 256)
#define ORDER_SZ (Nn + 176)                // buckets padded to x16 (11*15=165 max pad); /16 exact
#define NB_MF (ORDER_SZ / 16)              // block = 16 slots (degree-uniform), 4 waves
#define NB_RG (Nn / 16)                    // block = 4 waves; 16 nodes/block (MFMA tile)
#define NB_RELSEG (Ne / 256)               // 3125 edge blocks
#define NB_EMBED (Nn / 4)                  // 12500 embed blocks
#define WT_PER_LAYER (Hd * 5 * Hd)         // 20480 halves: [64 cols][320 k]
#define MFWT_PER_LAYER ((MAXD + 1) * Hd * 2 * Hd)  // 90112 halves: [d][64 cols][128 k]
#define PREP_TOTAL (2 * WT_PER_LAYER + 2 * MFWT_PER_LAYER)

typedef _Float16 f16x8 __attribute__((ext_vector_type(8)));
typedef float f32x4 __attribute__((ext_vector_type(4)));

__device__ __forceinline__ float reluf(float v) { return v > 0.f ? v : 0.f; }
__device__ __forceinline__ int rfl(int v) { return __builtin_amdgcn_readfirstlane(v); }

// ---- FUSED: per-edge relation argmax/histogram/rank  +  embedding lookup ----
// (fp32 h write dropped: only the fp16 shadow is consumed downstream.)
__global__ void k_rel_emb(const float4* __restrict__ ea, const int* __restrict__ eidx,
                          int* __restrict__ seg, int* __restrict__ rank,
                          int* __restrict__ cnt,
                          const float* __restrict__ x, const float* __restrict__ emb,
                          __half* __restrict__ h16) {
    if (blockIdx.x < NB_RELSEG) {
        int e = blockIdx.x * 256 + threadIdx.x;     // grid sized exactly: e < Ne
        float4 a = ea[e];
        int bi = 0; float bv = a.x;
        if (a.y > bv) { bv = a.y; bi = 1; }
        if (a.z > bv) { bv = a.z; bi = 2; }
        if (a.w > bv) { bv = a.w; bi = 3; }
        int s = eidx[Ne + e] * Rr + bi;
        seg[e] = s;
        rank[e] = atomicAdd(&cnt[s], 1);
    } else {
        int wave = ((blockIdx.x - NB_RELSEG) * 256 + threadIdx.x) >> 6;  // < Nn
        int lane = threadIdx.x & 63;
        float v = (lane < NFd) ? x[(size_t)wave * NFd + lane] : -1e30f;
        int idx = lane;
        #pragma unroll
        for (int off = 16; off >= 1; off >>= 1) {
            float ov = __shfl_down(v, off);
            int oi = __shfl_down(idx, off);
            if (ov > v || (ov == v && oi < idx)) { v = ov; idx = oi; }
        }
        idx = __shfl(idx, 0);
        float hv = reluf(emb[(size_t)idx * Hd + lane]);
        h16[(size_t)wave * Hd + lane] = __float2half(hv);
    }
}

// ---- prep: fp16 transposed-stacked weights for both MFMA transforms ----
// wt  [layer][c][320]:  k<64 -> Wroot[k][c]; k=64+64r+kk -> W[r][kk][c]
// mfwt[layer][d][c][128]: k<64 -> Wl[d][k][c]; k>=64 -> Wr[d][k-64][c]
__global__ void k_prep(const float* __restrict__ w0, const float* __restrict__ r0,
                       const float* __restrict__ w1, const float* __restrict__ r1,
                       const float* __restrict__ wl0, const float* __restrict__ wr0,
                       const float* __restrict__ wl1, const float* __restrict__ wr1,
                       __half* __restrict__ wt, __half* __restrict__ mfwt) {
    int idx = blockIdx.x * 256 + threadIdx.x;
    if (idx < 2 * WT_PER_LAYER) {
        int b = idx / WT_PER_LAYER;
        int rem = idx % WT_PER_LAYER;
        int c = rem / 320;
        int k = rem % 320;
        const float* W  = b ? w1 : w0;
        const float* Rt = b ? r1 : r0;
        float v = (k < 64) ? Rt[k * Hd + c]
                           : W[((size_t)((k - 64) >> 6)) * Hd * Hd + ((k - 64) & 63) * Hd + c];
        wt[idx] = __float2half(v);
    } else if (idx < PREP_TOTAL) {
        int j = idx - 2 * WT_PER_LAYER;
        int b = j / MFWT_PER_LAYER;
        int rem = j % MFWT_PER_LAYER;
        int d = rem / (Hd * 128);
        int r2 = rem % (Hd * 128);
        int c = r2 / 128;
        int k = r2 % 128;
        const float* Wl = b ? wl1 : wl0;
        const float* Wr = b ? wr1 : wr0;
        float v = (k < 64) ? Wl[(size_t)d * Hd * Hd + k * Hd + c]
                           : Wr[(size_t)d * Hd * Hd + (k - 64) * Hd + c];
        mfwt[j] = __float2half(v);
    }
}

// ---- scan level 1 + fused degree histogram ----
__global__ void k_scan1(const int* __restrict__ cnt, int* __restrict__ off,
                        int* __restrict__ bsum, int* __restrict__ bcnt) {
    __shared__ int s[256];
    __shared__ int hist[16];
    int t = threadIdx.x;
    if (t < 16) hist[t] = 0;
    int idx = blockIdx.x * 256 + t;
    int v = (idx < NSEG) ? cnt[idx] : 0;
    s[t] = v;
    __syncthreads();
    if ((t & 3) == 0 && idx < NSEG) {
        int dsum = s[t] + s[t + 1] + s[t + 2] + s[t + 3];
        atomicAdd(&hist[min(dsum, MAXD)], 1);
    }
    #pragma unroll
    for (int o = 1; o < 256; o <<= 1) {
        int x = (t >= o) ? s[t - o] : 0;
        __syncthreads();
        s[t] += x;
        __syncthreads();
    }
    if (idx < NSEG) off[idx] = s[t] - v;            // exclusive
    if (t == 255) bsum[blockIdx.x] = s[255];
    if (t < 16) {
        int h = hist[t];
        if (h > 0) atomicAdd(&bcnt[t], h);
    }
}

// ---- scan level 2 + fused bucket prefix (16-aligned) + order pad-slot writes ----
__global__ void k_scan2(int* __restrict__ bsum, const int* __restrict__ bcnt,
                        int* __restrict__ bbase, int* __restrict__ order) {
    __shared__ int s[1024];
    int t = threadIdx.x;
    int v = (t < SCAN_BLK) ? bsum[t] : 0;
    s[t] = v;
    __syncthreads();
    #pragma unroll
    for (int o = 1; o < 1024; o <<= 1) {
        int x = (t >= o) ? s[t - o] : 0;
        __syncthreads();
        s[t] += x;
        __syncthreads();
    }
    if (t < SCAN_BLK) bsum[t] = s[t] - v;           // exclusive block bases
    if (t == 0) {
        int run = 0;
        for (int d = 0; d <= MAXD; d++) {
            int c = bcnt[d];
            bbase[d] = run;
            int pad = (c + 15) & ~15;               // x16: MFMA tile = degree-uniform
            for (int i = c; i < pad; i++) order[run + i] = -1;
            run += pad;
        }
        for (int i = run; i < ORDER_SZ; i++) order[i] = -1;
    }
}

// ---- FUSED: scan level 3 (final off)  +  degree-bucket scatter ----
__global__ void k_scan3_bucket(int* __restrict__ off, const int* __restrict__ bsum,
                               const int4* __restrict__ cnt4, const int* __restrict__ bbase,
                               int* __restrict__ bfill, int* __restrict__ order) {
    __shared__ int hist[16];
    __shared__ int base[16];
    int t = threadIdx.x;
    if (t < 16) hist[t] = 0;
    __syncthreads();
    int idx = blockIdx.x * 256 + t;
    if (idx == 0) off[NSEG] = Ne;
    if (idx < NSEG) off[idx] = off[idx] + bsum[blockIdx.x];
    int d = 0, rk = 0;
    bool valid = (idx < Nn);
    if (valid) {
        int4 c = cnt4[idx];
        d = min(c.x + c.y + c.z + c.w, MAXD);
        rk = atomicAdd(&hist[d], 1);
    }
    __syncthreads();
    if (t < 16) {
        int h = hist[t];
        base[t] = (h > 0) ? atomicAdd(&bfill[t], h) : 0;
    }
    __syncthreads();
    if (valid) order[bbase[d] + base[d] + rk] = idx | (d << 20);
}

// ---- scatter edges into segment-sorted order: NO atomics (rank precomputed) ----
__global__ void k_scatter(const int* __restrict__ eidx, const int* __restrict__ seg,
                          const int* __restrict__ rank, const int* __restrict__ off,
                          int* __restrict__ sorted_src) {
    int e = blockIdx.x * 256 + threadIdx.x;
    if (e >= Ne) return;
    int pos = off[seg[e]] + rank[e];
    sorted_src[pos] = eidx[e];
}

#define H16(ptr, s) __half2float((ptr)[(size_t)(s) * Hd + lane])

// ---- FUSED RGCN layer: prefix-snapshot gather -> fp16 LDS -> MFMA transform ----
__global__ __launch_bounds__(256) void k_rgcn_fused(
        const __half* __restrict__ hin16,
        const int* __restrict__ off, const int* __restrict__ ssrc,
        const __half* __restrict__ wt, const float* __restrict__ bias,
        float* __restrict__ hout, __half* __restrict__ hout16) {
    __shared__ __align__(16) __half alds[16 * 296];  // [node]: rel*72 + k; node stride 296
    int tid = threadIdx.x;
    int wv = tid >> 6, lane = tid & 63;
    int nblk = rfl(blockIdx.x * 16);
    int n0 = nblk + wv * 4;
    int ob[17];                                     // wave-uniform segment boundaries
    #pragma unroll
    for (int k = 0; k < 17; k++) ob[k] = rfl(off[4 * n0 + k]);

    float acc = 0.f, snap = 0.f;
    int segi = 0;
    int nb = ob[1];
    int e = ob[0], eEnd = ob[16];

#define EMIT_SEG do {                                                \
        float d_ = acc - snap; snap = acc;                           \
        int cN_ = ob[segi + 1] - ob[segi];                           \
        float iv_ = (cN_ > 0) ? 1.f / (float)cN_ : 0.f;              \
        alds[(wv * 4 + (segi >> 2)) * 296 + (segi & 3) * 72 + lane]  \
            = __float2half(d_ * iv_);                                \
        segi++;                                                      \
        nb = (segi < 16) ? ob[segi + 1] : 0x7fffffff;                \
    } while (0)

    if (e + 16 <= eEnd) {
        int4 iA = *(const int4*)(ssrc + e);
        int4 iB = *(const int4*)(ssrc + e + 4);
        int4 iC = *(const int4*)(ssrc + e + 8);
        int4 iD = *(const int4*)(ssrc + e + 12);
        while (true) {
            int en = e + 16;
            bool more = (en + 16 <= eEnd);
            int4 jA, jB, jC, jD;
            if (more) {                             // prefetch next chunk's indices
                jA = *(const int4*)(ssrc + en);
                jB = *(const int4*)(ssrc + en + 4);
                jC = *(const int4*)(ssrc + en + 8);
                jD = *(const int4*)(ssrc + en + 12);
            }
            float v0 = H16(hin16, iA.x);
            float v1 = H16(hin16, iA.y);
            float v2 = H16(hin16, iA.z);
            float v3 = H16(hin16, iA.w);
            float v4 = H16(hin16, iB.x);
            float v5 = H16(hin16, iB.y);
            float v6 = H16(hin16, iB.z);
            float v7 = H16(hin16, iB.w);
            float v8 = H16(hin16, iC.x);
            float v9 = H16(hin16, iC.y);
            float vA = H16(hin16, iC.z);
            float vB = H16(hin16, iC.w);
            float vC = H16(hin16, iD.x);
            float vD = H16(hin16, iD.y);
            float vE = H16(hin16, iD.z);
            float vF = H16(hin16, iD.w);
            // ordered prefix adds; boundary checks are wave-uniform scalar compares
            while (e + 0  == nb) EMIT_SEG;  acc += v0;
            while (e + 1  == nb) EMIT_SEG;  acc += v1;
            while (e + 2  == nb) EMIT_SEG;  acc += v2;
            while (e + 3  == nb) EMIT_SEG;  acc += v3;
            while (e + 4  == nb) EMIT_SEG;  acc += v4;
            while (e + 5  == nb) EMIT_SEG;  acc += v5;
            while (e + 6  == nb) EMIT_SEG;  acc += v6;
            while (e + 7  == nb) EMIT_SEG;  acc += v7;
            while (e + 8  == nb) EMIT_SEG;  acc += v8;
            while (e + 9  == nb) EMIT_SEG;  acc += v9;
            while (e + 10 == nb) EMIT_SEG;  acc += vA;
            while (e + 11 == nb) EMIT_SEG;  acc += vB;
            while (e + 12 == nb) EMIT_SEG;  acc += vC;
            while (e + 13 == nb) EMIT_SEG;  acc += vD;
            while (e + 14 == nb) EMIT_SEG;  acc += vE;
            while (e + 15 == nb) EMIT_SEG;  acc += vF;
            e = en;
            if (!more) break;
            iA = jA; iB = jB; iC = jC; iD = jD;
        }
    }
    for (; e < eEnd; e++) {                         // tail (< 16 edges)
        while (e == nb) EMIT_SEG;
        int s = rfl(ssrc[e]);
        acc += H16(hin16, s);
    }
    while (segi < 16) EMIT_SEG;                     // trailing (possibly empty) segments
#undef EMIT_SEG

    __syncthreads();                                // waves share the A tile now

    // ---- MFMA transform: wave wv -> output cols [16wv, 16wv+16), 16 nodes ----
    int rp = lane & 15;
    int g  = lane >> 4;
    const __half* ha = hin16 + (size_t)(nblk + rp) * Hd + 8 * g;
    const __half* ba = wt + (size_t)(wv * 16 + rp) * 320 + 8 * g;
    const __half* aa = alds + rp * 296 + 8 * g;
    f32x4 dacc = {0.f, 0.f, 0.f, 0.f};
    #pragma unroll
    for (int s = 0; s < 10; s++) {                  // k0 = 32*s; a-source matches (32s)
        f16x8 bfrag = *(const f16x8*)(ba + s * 32);
        f16x8 afrag;
        if (s < 2) afrag = *(const f16x8*)(ha + s * 32);
        else       afrag = *(const f16x8*)(aa + ((s - 2) >> 1) * 72 + ((s - 2) & 1) * 32);
        dacc = __builtin_amdgcn_mfma_f32_16x16x32_f16(afrag, bfrag, dacc, 0, 0, 0);
    }
    int c = wv * 16 + rp;
    float bb = bias[c];
    #pragma unroll
    for (int j = 0; j < 4; j++) {
        int row = nblk + g * 4 + j;
        float v = reluf(dacc[j] + bb);
        hout[(size_t)row * Hd + c] = v;
        hout16[(size_t)row * Hd + c] = __float2half(v);
    }
}

// ---- FUSED MFConv layer: fp16 gather -> shared fp16 LDS A-tile -> MFMA ----
// Block = 16 degree-uniform order slots (buckets padded x16; pad is bucket suffix,
// so slot 0 valid => d for whole tile; slot0 invalid => whole block is pad).
// out = agg@Wl[d] + h@Wr[d] + bl[d] via 4x mfma_f32_16x16x32_f16 (K=128 stacked).
__global__ __launch_bounds__(256) void k_mf_fused(
        const __half* __restrict__ hin16,
        const int* __restrict__ off, const int* __restrict__ ssrc,
        const int* __restrict__ order, const __half* __restrict__ mfwt,
        const float* __restrict__ bl,
        float* __restrict__ hout, __half* __restrict__ hout16, int relu_out) {
    __shared__ __align__(16) __half alds[16 * 72];  // 2.25 KB: [slot][k], stride 72
    int tid = threadIdx.x;
    int wv = tid >> 6, lane = tid & 63;
    int blk = rfl(blockIdx.x * 16);
    int ent0 = rfl(order[blk]);
    if (ent0 < 0) return;                           // entire block is pad
    int d = ent0 >> 20;
    for (int i = 0; i < 4; i++) {                   // wave gathers its 4 slots
        int slot = blk + wv * 4 + i;
        int ent = rfl(order[slot]);
        float sum = 0.f;
        if (ent >= 0) {
            int n = ent & 0xFFFFF;
            int e0 = rfl(off[n * Rr]);
            int e4 = rfl(off[n * Rr + Rr]);
            float p0 = 0.f, p1 = 0.f, p2 = 0.f, p3 = 0.f;
            int e = e0;
            for (; e + 16 <= e4; e += 16) {
                const int4 sA = *(const int4*)(ssrc + e);
                const int4 sB = *(const int4*)(ssrc + e + 4);
                const int4 sC = *(const int4*)(ssrc + e + 8);
                const int4 sD = *(const int4*)(ssrc + e + 12);
                p0 += H16(hin16, sA.x) + H16(hin16, sA.y) + H16(hin16, sA.z) + H16(hin16, sA.w);
                p1 += H16(hin16, sB.x) + H16(hin16, sB.y) + H16(hin16, sB.z) + H16(hin16, sB.w);
                p2 += H16(hin16, sC.x) + H16(hin16, sC.y) + H16(hin16, sC.z) + H16(hin16, sC.w);
                p3 += H16(hin16, sD.x) + H16(hin16, sD.y) + H16(hin16, sD.z) + H16(hin16, sD.w);
            }
            for (; e + 4 <= e4; e += 4) {
                const int4 sA = *(const int4*)(ssrc + e);
                p0 += H16(hin16, sA.x) + H16(hin16, sA.y) + H16(hin16, sA.z) + H16(hin16, sA.w);
            }
            for (; e < e4; e++) {
                int s = rfl(ssrc[e]);
                p0 += H16(hin16, s);
            }
            sum = (p0 + p1) + (p2 + p3);
        }
        alds[(wv * 4 + i) * 72 + lane] = __float2half(sum);
    }
    __syncthreads();

    // ---- MFMA: wave wv -> output cols [16wv,16wv+16), rows = 16 tile slots ----
    int rp = lane & 15;
    int g  = lane >> 4;
    int entr = order[blk + rp];                     // per-lane row entry (L2-hot)
    int nr = (entr >= 0) ? (entr & 0xFFFFF) : 0;
    const __half* aa = alds + rp * 72 + 8 * g;
    const __half* ha = hin16 + (size_t)nr * Hd + 8 * g;
    const __half* ba = mfwt + ((size_t)d * Hd + wv * 16 + rp) * 128 + 8 * g;
    f32x4 dacc = {0.f, 0.f, 0.f, 0.f};
    #pragma unroll
    for (int s = 0; s < 4; s++) {                   // K=128: k<64 agg@Wl, k>=64 h@Wr
        f16x8 bfrag = *(const f16x8*)(ba + s * 32);
        f16x8 afrag = (s < 2) ? *(const f16x8*)(aa + s * 32)
                              : *(const f16x8*)(ha + (s - 2) * 32);
        dacc = __builtin_amdgcn_mfma_f32_16x16x32_f16(afrag, bfrag, dacc, 0, 0, 0);
    }
    int c = wv * 16 + rp;
    float bb = bl[d * Hd + c];
    #pragma unroll
    for (int j = 0; j < 4; j++) {
        int entw = order[blk + g * 4 + j];
        if (entw >= 0) {
            int n = entw & 0xFFFFF;
            float v = dacc[j] + bb;
            if (relu_out) {
                v = reluf(v);
                hout16[(size_t)n * Hd + c] = __float2half(v);  // next gather's shadow
            }
            hout[(size_t)n * Hd + c] = v;
        }
    }
}

// ---- global add pool (batch_idx is sorted -> mostly single fused atomic) ----
__global__ void k_pool(const float* __restrict__ h, const int* __restrict__ batch,
                       float* __restrict__ g) {
    int wave = rfl((blockIdx.x * 256 + threadIdx.x) >> 6);
    int lane = threadIdx.x & 63;
    int n0 = wave * 4;
    if (n0 >= Nn) return;
    int b0 = batch[n0], b1 = batch[n0 + 1], b2 = batch[n0 + 2], b3 = batch[n0 + 3];
    float v0 = h[(size_t)n0 * Hd + lane];
    float v1 = h[(size_t)(n0 + 1) * Hd + lane];
    float v2 = h[(size_t)(n0 + 2) * Hd + lane];
    float v3 = h[(size_t)(n0 + 3) * Hd + lane];
    if (b0 == b1 && b0 == b2 && b0 == b3) {
        unsafeAtomicAdd(&g[(size_t)b0 * Hd + lane], v0 + v1 + v2 + v3);
    } else {
        unsafeAtomicAdd(&g[(size_t)b0 * Hd + lane], v0);
        unsafeAtomicAdd(&g[(size_t)b1 * Hd + lane], v1);
        unsafeAtomicAdd(&g[(size_t)b2 * Hd + lane], v2);
        unsafeAtomicAdd(&g[(size_t)b3 * Hd + lane], v3);
    }
}

// ---- head: relu(g@lin1+b1)@lin2+b2, one wave per graph ----
__global__ void k_head(const float* __restrict__ g, const float* __restrict__ w1,
                       const float* __restrict__ b1, const float* __restrict__ w2,
                       const float* __restrict__ b2, float* __restrict__ out) {
    __shared__ float t[4][Hd];
    int wv = threadIdx.x >> 6;
    int lane = threadIdx.x & 63;
    int gi = blockIdx.x * 4 + wv;
    float acc = b1[lane];
    for (int k = 0; k < Hd; k++) acc += g[(size_t)gi * Hd + k] * w1[k * Hd + lane];
    t[wv][lane] = reluf(acc);
    __syncthreads();
    if (lane < Od) {
        float o = b2[lane];
        for (int k = 0; k < Hd; k++) o += t[wv][k] * w2[k * Od + lane];
        out[(size_t)gi * Od + lane] = o;
    }
}

extern "C" void kernel_launch(void* const* d_in, const int* in_sizes, int n_in,
                              void* d_out, int out_size, void* d_ws, size_t ws_size,
                              hipStream_t stream) {
    const float* x      = (const float*)d_in[0];
    const float* ea     = (const float*)d_in[1];
    const int*   eidx   = (const int*)d_in[2];
    const int*   batch  = (const int*)d_in[3];
    const float* emb    = (const float*)d_in[4];
    const float* lin1_w = (const float*)d_in[5];
    const float* lin1_b = (const float*)d_in[6];
    const float* lin2_w = (const float*)d_in[7];
    const float* lin2_b = (const float*)d_in[8];
    const float* rgcn_w[2]    = {(const float*)d_in[9],  (const float*)d_in[15]};
    const float* rgcn_root[2] = {(const float*)d_in[10], (const float*)d_in[16]};
    const float* rgcn_b[2]    = {(const float*)d_in[11], (const float*)d_in[17]};
    const float* mf_wl[2]     = {(const float*)d_in[12], (const float*)d_in[18]};
    const float* mf_bl[2]     = {(const float*)d_in[13], (const float*)d_in[19]};
    const float* mf_wr[2]     = {(const float*)d_in[14], (const float*)d_in[20]};

    char* p = (char*)d_ws;
    float* h0    = (float*)p; p += sizeof(float) * (size_t)Nn * Hd;
    float* h1    = (float*)p; p += sizeof(float) * (size_t)Nn * Hd;
    __half* h16a = (__half*)p; p += sizeof(__half) * (size_t)Nn * Hd;
    __half* h16b = (__half*)p; p += sizeof(__half) * (size_t)Nn * Hd;
    float* gbuf  = (float*)p; p += sizeof(float) * (size_t)Ng * Hd;
    __half* wt16 = (__half*)p; p += sizeof(__half) * (size_t)2 * WT_PER_LAYER;
    __half* mfwt16 = (__half*)p; p += sizeof(__half) * (size_t)2 * MFWT_PER_LAYER;
    int* seg     = (int*)p;   p += sizeof(int) * (size_t)Ne;
    int* rank    = (int*)p;   p += sizeof(int) * (size_t)Ne;
    int* ssrc    = (int*)p;   p += sizeof(int) * (size_t)Ne;
    int* cnt     = (int*)p;   p += sizeof(int) * (size_t)NSEG;  // contiguous with bcnt/bfill
    int* bcnt    = (int*)p;   p += sizeof(int) * 16;
    int* bfill   = (int*)p;   p += sizeof(int) * 16;
    int* off     = (int*)p;   p += sizeof(int) * (size_t)(NSEG + 1);
    int* bsum    = (int*)p;   p += sizeof(int) * 1024;
    int* bbase   = (int*)p;   p += sizeof(int) * 16;
    int* order   = (int*)p;   p += sizeof(int) * (size_t)ORDER_SZ;

    hipMemsetAsync(cnt, 0, sizeof(int) * ((size_t)NSEG + 32), stream);
    hipMemsetAsync(gbuf, 0, sizeof(float) * (size_t)Ng * Hd, stream);

    k_prep<<<(PREP_TOTAL + 255) / 256, 256, 0, stream>>>(
        rgcn_w[0], rgcn_root[0], rgcn_w[1], rgcn_root[1],
        mf_wl[0], mf_wr[0], mf_wl[1], mf_wr[1], wt16, mfwt16);
    k_rel_emb<<<NB_RELSEG + NB_EMBED, 256, 0, stream>>>((const float4*)ea, eidx, seg, rank,
                                                        cnt, x, emb, h16a);
    k_scan1<<<SCAN_BLK, 256, 0, stream>>>(cnt, off, bsum, bcnt);
    k_scan2<<<1, 1024, 0, stream>>>(bsum, bcnt, bbase, order);
    k_scan3_bucket<<<SCAN_BLK, 256, 0, stream>>>(off, bsum, (const int4*)cnt, bbase,
                                                 bfill, order);
    k_scatter<<<Ne / 256, 256, 0, stream>>>(eidx, seg, rank, off, ssrc);

    float* h32a = h0;  float* h32b = h1;
    __half* hin16 = h16a;  __half* hout16 = h16b;
    for (int b = 0; b < 2; b++) {
        k_rgcn_fused<<<NB_RG, 256, 0, stream>>>(hin16, off, ssrc, wt16 + b * WT_PER_LAYER,
                                                rgcn_b[b], h32b, hout16);
        k_mf_fused<<<NB_MF, 256, 0, stream>>>(hout16, off, ssrc, order,
                                              mfwt16 + b * MFWT_PER_LAYER, mf_bl[b],
                                              h32a, hin16, b == 0 ? 1 : 0);
        // mf output: fp32 in h32a (pool path), fp16 shadow back in hin16 (b=0 only)
    }
    k_pool<<<Nn / 16, 256, 0, stream>>>(h32a, batch, gbuf);
    k_head<<<Ng / 4, 256, 0, stream>>>(gbuf, lin1_w, lin1_b, lin2_w, lin2_b, (float*)d_out);
}

// Round 6
// 345.719 us; speedup vs baseline: 1.3700x; 1.0298x over previous
//
#include <hip/hip_runtime.h>
#include <hip/hip_fp16.h>
#include <cstdint>
#include <cstddef>

#define Nn 50000
#define Ne 800000
#define Ng 1024
#define NFd 32
#define Rr 4
#define Hd 64
#define Od 16
#define MAXD 10
#define NSEG (Nn * Rr)
#define SCAN_BLK ((NSEG + 255) / 256)
#define ORDER_SZ (Nn + 176)                // buckets padded to x16 (11*15=165 max pad); /16 exact
#define NB_MF (ORDER_SZ / 16)              // block = 16 slots (degree-uniform), 4 waves
#define NB_RG (Nn / 16)                    // block = 4 waves; 16 nodes/block (MFMA tile)
#define NB_RELSEG (Ne / 256)               // 3125 edge blocks
#define NB_EMBED (Nn / 4)                  // 12500 embed blocks
#define WT_PER_LAYER (Hd * 5 * Hd)         // 20480 halves: [64 cols][320 k]
#define MFWT_PER_LAYER ((MAXD + 1) * Hd * 2 * Hd)  // 90112 halves: [d][64 cols][128 k]
#define PREP_TOTAL (2 * WT_PER_LAYER + 2 * MFWT_PER_LAYER)

typedef _Float16 f16x8 __attribute__((ext_vector_type(8)));
typedef float f32x4 __attribute__((ext_vector_type(4)));

__device__ __forceinline__ float reluf(float v) { return v > 0.f ? v : 0.f; }
__device__ __forceinline__ int rfl(int v) { return __builtin_amdgcn_readfirstlane(v); }

// ---- FUSED: per-edge relation argmax/histogram/rank  +  embedding lookup ----
// (fp32 h write dropped: only the fp16 shadow is consumed downstream.)
__global__ void k_rel_emb(const float4* __restrict__ ea, const int* __restrict__ eidx,
                          int* __restrict__ seg, int* __restrict__ rank,
                          int* __restrict__ cnt,
                          const float* __restrict__ x, const float* __restrict__ emb,
                          __half* __restrict__ h16) {
    if (blockIdx.x < NB_RELSEG) {
        int e = blockIdx.x * 256 + threadIdx.x;     // grid sized exactly: e < Ne
        float4 a = ea[e];
        int bi = 0; float bv = a.x;
        if (a.y > bv) { bv = a.y; bi = 1; }
        if (a.z > bv) { bv = a.z; bi = 2; }
        if (a.w > bv) { bv = a.w; bi = 3; }
        int s = eidx[Ne + e] * Rr + bi;
        seg[e] = s;
        rank[e] = atomicAdd(&cnt[s], 1);
    } else {
        int wave = ((blockIdx.x - NB_RELSEG) * 256 + threadIdx.x) >> 6;  // < Nn
        int lane = threadIdx.x & 63;
        float v = (lane < NFd) ? x[(size_t)wave * NFd + lane] : -1e30f;
        int idx = lane;
        #pragma unroll
        for (int off = 16; off >= 1; off >>= 1) {
            float ov = __shfl_down(v, off);
            int oi = __shfl_down(idx, off);
            if (ov > v || (ov == v && oi < idx)) { v = ov; idx = oi; }
        }
        idx = __shfl(idx, 0);
        float hv = reluf(emb[(size_t)idx * Hd + lane]);
        h16[(size_t)wave * Hd + lane] = __float2half(hv);
    }
}

// ---- prep: fp16 transposed-stacked weights for both MFMA transforms ----
// wt  [layer][c][320]:  k<64 -> Wroot[k][c]; k=64+64r+kk -> W[r][kk][c]
// mfwt[layer][d][c][128]: k<64 -> Wl[d][k][c]; k>=64 -> Wr[d][k-64][c]
__global__ void k_prep(const float* __restrict__ w0, const float* __restrict__ r0,
                       const float* __restrict__ w1, const float* __restrict__ r1,
                       const float* __restrict__ wl0, const float* __restrict__ wr0,
                       const float* __restrict__ wl1, const float* __restrict__ wr1,
                       __half* __restrict__ wt, __half* __restrict__ mfwt) {
    int idx = blockIdx.x * 256 + threadIdx.x;
    if (idx < 2 * WT_PER_LAYER) {
        int b = idx / WT_PER_LAYER;
        int rem = idx % WT_PER_LAYER;
        int c = rem / 320;
        int k = rem % 320;
        const float* W  = b ? w1 : w0;
        const float* Rt = b ? r1 : r0;
        float v = (k < 64) ? Rt[k * Hd + c]
                           : W[((size_t)((k - 64) >> 6)) * Hd * Hd + ((k - 64) & 63) * Hd + c];
        wt[idx] = __float2half(v);
    } else if (idx < PREP_TOTAL) {
        int j = idx - 2 * WT_PER_LAYER;
        int b = j / MFWT_PER_LAYER;
        int rem = j % MFWT_PER_LAYER;
        int d = rem / (Hd * 128);
        int r2 = rem % (Hd * 128);
        int c = r2 / 128;
        int k = r2 % 128;
        const float* Wl = b ? wl1 : wl0;
        const float* Wr = b ? wr1 : wr0;
        float v = (k < 64) ? Wl[(size_t)d * Hd * Hd + k * Hd + c]
                           : Wr[(size_t)d * Hd * Hd + (k - 64) * Hd + c];
        mfwt[j] = __float2half(v);
    }
}

// ---- scan level 1 + fused degree histogram ----
__global__ void k_scan1(const int* __restrict__ cnt, int* __restrict__ off,
                        int* __restrict__ bsum, int* __restrict__ bcnt) {
    __shared__ int s[256];
    __shared__ int hist[16];
    int t = threadIdx.x;
    if (t < 16) hist[t] = 0;
    int idx = blockIdx.x * 256 + t;
    int v = (idx < NSEG) ? cnt[idx] : 0;
    s[t] = v;
    __syncthreads();
    if ((t & 3) == 0 && idx < NSEG) {
        int dsum = s[t] + s[t + 1] + s[t + 2] + s[t + 3];
        atomicAdd(&hist[min(dsum, MAXD)], 1);
    }
    #pragma unroll
    for (int o = 1; o < 256; o <<= 1) {
        int x = (t >= o) ? s[t - o] : 0;
        __syncthreads();
        s[t] += x;
        __syncthreads();
    }
    if (idx < NSEG) off[idx] = s[t] - v;            // exclusive
    if (t == 255) bsum[blockIdx.x] = s[255];
    if (t < 16) {
        int h = hist[t];
        if (h > 0) atomicAdd(&bcnt[t], h);
    }
}

// ---- scan level 2 + fused bucket prefix (16-aligned) + order pad-slot writes ----
__global__ void k_scan2(int* __restrict__ bsum, const int* __restrict__ bcnt,
                        int* __restrict__ bbase, int* __restrict__ order) {
    __shared__ int s[1024];
    int t = threadIdx.x;
    int v = (t < SCAN_BLK) ? bsum[t] : 0;
    s[t] = v;
    __syncthreads();
    #pragma unroll
    for (int o = 1; o < 1024; o <<= 1) {
        int x = (t >= o) ? s[t - o] : 0;
        __syncthreads();
        s[t] += x;
        __syncthreads();
    }
    if (t < SCAN_BLK) bsum[t] = s[t] - v;           // exclusive block bases
    if (t == 0) {
        int run = 0;
        for (int d = 0; d <= MAXD; d++) {
            int c = bcnt[d];
            bbase[d] = run;
            int pad = (c + 15) & ~15;               // x16: MFMA tile = degree-uniform
            for (int i = c; i < pad; i++) order[run + i] = -1;
            run += pad;
        }
        for (int i = run; i < ORDER_SZ; i++) order[i] = -1;
    }
}

// ---- FUSED: scan level 3 (final off)  +  degree-bucket scatter ----
__global__ void k_scan3_bucket(int* __restrict__ off, const int* __restrict__ bsum,
                               const int4* __restrict__ cnt4, const int* __restrict__ bbase,
                               int* __restrict__ bfill, int* __restrict__ order) {
    __shared__ int hist[16];
    __shared__ int base[16];
    int t = threadIdx.x;
    if (t < 16) hist[t] = 0;
    __syncthreads();
    int idx = blockIdx.x * 256 + t;
    if (idx == 0) off[NSEG] = Ne;
    if (idx < NSEG) off[idx] = off[idx] + bsum[blockIdx.x];
    int d = 0, rk = 0;
    bool valid = (idx < Nn);
    if (valid) {
        int4 c = cnt4[idx];
        d = min(c.x + c.y + c.z + c.w, MAXD);
        rk = atomicAdd(&hist[d], 1);
    }
    __syncthreads();
    if (t < 16) {
        int h = hist[t];
        base[t] = (h > 0) ? atomicAdd(&bfill[t], h) : 0;
    }
    __syncthreads();
    if (valid) order[bbase[d] + base[d] + rk] = idx | (d << 20);
}

// ---- scatter edges into segment-sorted order: NO atomics (rank precomputed) ----
__global__ void k_scatter(const int* __restrict__ eidx, const int* __restrict__ seg,
                          const int* __restrict__ rank, const int* __restrict__ off,
                          int* __restrict__ sorted_src) {
    int e = blockIdx.x * 256 + threadIdx.x;
    if (e >= Ne) return;
    int pos = off[seg[e]] + rank[e];
    sorted_src[pos] = eidx[e];
}

#define H16(ptr, s) __half2float((ptr)[(size_t)(s) * Hd + lane])

// ---- FUSED RGCN layer: prefix-snapshot gather -> fp16 LDS -> MFMA transform ----
// Scratch fix: segment boundaries live in LANES (obv, lane k = off[4n0+k]) and are
// fetched at emit time via dynamic __shfl -- no runtime-indexed private array.
__global__ __launch_bounds__(256) void k_rgcn_fused(
        const __half* __restrict__ hin16,
        const int* __restrict__ off, const int* __restrict__ ssrc,
        const __half* __restrict__ wt, const float* __restrict__ bias,
        float* __restrict__ hout, __half* __restrict__ hout16) {
    __shared__ __align__(16) __half alds[16 * 296];  // [node]: rel*72 + k; node stride 296
    int tid = threadIdx.x;
    int wv = tid >> 6, lane = tid & 63;
    int nblk = rfl(blockIdx.x * 16);
    int n0 = nblk + wv * 4;
    // boundaries in lanes: lane k (k<=16) holds off[4*n0+k]; lanes >16 replicate b16
    int obv = off[4 * n0 + min(lane, 16)];
    int cntv = __shfl(obv, lane + 1) - obv;         // lane<16: edges in segment 'lane'
    float ivv = (cntv > 0) ? 1.f / (float)cntv : 0.f;
    int e    = rfl(__shfl(obv, 0));
    int eEnd = rfl(__shfl(obv, 16));

    float acc = 0.f, snap = 0.f;
    int segi = 0;
    int nb = rfl(__shfl(obv, 1));

#define EMIT_SEG do {                                                \
        float d_ = acc - snap; snap = acc;                           \
        float iv_ = __shfl(ivv, segi);                               \
        alds[(wv * 4 + (segi >> 2)) * 296 + (segi & 3) * 72 + lane]  \
            = __float2half(d_ * iv_);                                \
        segi++;                                                      \
        nb = (segi < 16) ? rfl(__shfl(obv, segi + 1)) : 0x7fffffff;  \
    } while (0)

    if (e + 16 <= eEnd) {
        int4 iA = *(const int4*)(ssrc + e);
        int4 iB = *(const int4*)(ssrc + e + 4);
        int4 iC = *(const int4*)(ssrc + e + 8);
        int4 iD = *(const int4*)(ssrc + e + 12);
        while (true) {
            int en = e + 16;
            bool more = (en + 16 <= eEnd);
            int4 jA, jB, jC, jD;
            if (more) {                             // prefetch next chunk's indices
                jA = *(const int4*)(ssrc + en);
                jB = *(const int4*)(ssrc + en + 4);
                jC = *(const int4*)(ssrc + en + 8);
                jD = *(const int4*)(ssrc + en + 12);
            }
            float v0 = H16(hin16, iA.x);
            float v1 = H16(hin16, iA.y);
            float v2 = H16(hin16, iA.z);
            float v3 = H16(hin16, iA.w);
            float v4 = H16(hin16, iB.x);
            float v5 = H16(hin16, iB.y);
            float v6 = H16(hin16, iB.z);
            float v7 = H16(hin16, iB.w);
            float v8 = H16(hin16, iC.x);
            float v9 = H16(hin16, iC.y);
            float vA = H16(hin16, iC.z);
            float vB = H16(hin16, iC.w);
            float vC = H16(hin16, iD.x);
            float vD = H16(hin16, iD.y);
            float vE = H16(hin16, iD.z);
            float vF = H16(hin16, iD.w);
            // ordered prefix adds; boundary checks are wave-uniform compares
            while (e + 0  == nb) EMIT_SEG;  acc += v0;
            while (e + 1  == nb) EMIT_SEG;  acc += v1;
            while (e + 2  == nb) EMIT_SEG;  acc += v2;
            while (e + 3  == nb) EMIT_SEG;  acc += v3;
            while (e + 4  == nb) EMIT_SEG;  acc += v4;
            while (e + 5  == nb) EMIT_SEG;  acc += v5;
            while (e + 6  == nb) EMIT_SEG;  acc += v6;
            while (e + 7  == nb) EMIT_SEG;  acc += v7;
            while (e + 8  == nb) EMIT_SEG;  acc += v8;
            while (e + 9  == nb) EMIT_SEG;  acc += v9;
            while (e + 10 == nb) EMIT_SEG;  acc += vA;
            while (e + 11 == nb) EMIT_SEG;  acc += vB;
            while (e + 12 == nb) EMIT_SEG;  acc += vC;
            while (e + 13 == nb) EMIT_SEG;  acc += vD;
            while (e + 14 == nb) EMIT_SEG;  acc += vE;
            while (e + 15 == nb) EMIT_SEG;  acc += vF;
            e = en;
            if (!more) break;
            iA = jA; iB = jB; iC = jC; iD = jD;
        }
    }
    for (; e < eEnd; e++) {                         // tail (< 16 edges)
        while (e == nb) EMIT_SEG;
        int s = rfl(ssrc[e]);
        acc += H16(hin16, s);
    }
    while (segi < 16) EMIT_SEG;                     // trailing (possibly empty) segments
#undef EMIT_SEG

    __syncthreads();                                // waves share the A tile now

    // ---- MFMA transform: wave wv -> output cols [16wv, 16wv+16), 16 nodes ----
    int rp = lane & 15;
    int g  = lane >> 4;
    const __half* ha = hin16 + (size_t)(nblk + rp) * Hd + 8 * g;
    const __half* ba = wt + (size_t)(wv * 16 + rp) * 320 + 8 * g;
    const __half* aa = alds + rp * 296 + 8 * g;
    f32x4 dacc = {0.f, 0.f, 0.f, 0.f};
    #pragma unroll
    for (int s = 0; s < 10; s++) {                  // k0 = 32*s; a-source matches (32s)
        f16x8 bfrag = *(const f16x8*)(ba + s * 32);
        f16x8 afrag;
        if (s < 2) afrag = *(const f16x8*)(ha + s * 32);
        else       afrag = *(const f16x8*)(aa + ((s - 2) >> 1) * 72 + ((s - 2) & 1) * 32);
        dacc = __builtin_amdgcn_mfma_f32_16x16x32_f16(afrag, bfrag, dacc, 0, 0, 0);
    }
    int c = wv * 16 + rp;
    float bb = bias[c];
    #pragma unroll
    for (int j = 0; j < 4; j++) {
        int row = nblk + g * 4 + j;
        float v = reluf(dacc[j] + bb);
        hout[(size_t)row * Hd + c] = v;
        hout16[(size_t)row * Hd + c] = __float2half(v);
    }
}

// ---- FUSED MFConv layer: fp16 gather -> shared fp16 LDS A-tile -> MFMA ----
__global__ __launch_bounds__(256) void k_mf_fused(
        const __half* __restrict__ hin16,
        const int* __restrict__ off, const int* __restrict__ ssrc,
        const int* __restrict__ order, const __half* __restrict__ mfwt,
        const float* __restrict__ bl,
        float* __restrict__ hout, __half* __restrict__ hout16, int relu_out) {
    __shared__ __align__(16) __half alds[16 * 72];  // 2.25 KB: [slot][k], stride 72
    int tid = threadIdx.x;
    int wv = tid >> 6, lane = tid & 63;
    int blk = rfl(blockIdx.x * 16);
    int ent0 = rfl(order[blk]);
    if (ent0 < 0) return;                           // entire block is pad
    int d = ent0 >> 20;
    for (int i = 0; i < 4; i++) {                   // wave gathers its 4 slots
        int slot = blk + wv * 4 + i;
        int ent = rfl(order[slot]);
        float sum = 0.f;
        if (ent >= 0) {
            int n = ent & 0xFFFFF;
            int e0 = rfl(off[n * Rr]);
            int e4 = rfl(off[n * Rr + Rr]);
            float p0 = 0.f, p1 = 0.f, p2 = 0.f, p3 = 0.f;
            int e = e0;
            for (; e + 16 <= e4; e += 16) {
                const int4 sA = *(const int4*)(ssrc + e);
                const int4 sB = *(const int4*)(ssrc + e + 4);
                const int4 sC = *(const int4*)(ssrc + e + 8);
                const int4 sD = *(const int4*)(ssrc + e + 12);
                p0 += H16(hin16, sA.x) + H16(hin16, sA.y) + H16(hin16, sA.z) + H16(hin16, sA.w);
                p1 += H16(hin16, sB.x) + H16(hin16, sB.y) + H16(hin16, sB.z) + H16(hin16, sB.w);
                p2 += H16(hin16, sC.x) + H16(hin16, sC.y) + H16(hin16, sC.z) + H16(hin16, sC.w);
                p3 += H16(hin16, sD.x) + H16(hin16, sD.y) + H16(hin16, sD.z) + H16(hin16, sD.w);
            }
            for (; e + 4 <= e4; e += 4) {
                const int4 sA = *(const int4*)(ssrc + e);
                p0 += H16(hin16, sA.x) + H16(hin16, sA.y) + H16(hin16, sA.z) + H16(hin16, sA.w);
            }
            for (; e < e4; e++) {
                int s = rfl(ssrc[e]);
                p0 += H16(hin16, s);
            }
            sum = (p0 + p1) + (p2 + p3);
        }
        alds[(wv * 4 + i) * 72 + lane] = __float2half(sum);
    }
    __syncthreads();

    // ---- MFMA: wave wv -> output cols [16wv,16wv+16), rows = 16 tile slots ----
    int rp = lane & 15;
    int g  = lane >> 4;
    int entr = order[blk + rp];                     // per-lane row entry (L2-hot)
    int nr = (entr >= 0) ? (entr & 0xFFFFF) : 0;
    const __half* aa = alds + rp * 72 + 8 * g;
    const __half* ha = hin16 + (size_t)nr * Hd + 8 * g;
    const __half* ba = mfwt + ((size_t)d * Hd + wv * 16 + rp) * 128 + 8 * g;
    f32x4 dacc = {0.f, 0.f, 0.f, 0.f};
    #pragma unroll
    for (int s = 0; s < 4; s++) {                   // K=128: k<64 agg@Wl, k>=64 h@Wr
        f16x8 bfrag = *(const f16x8*)(ba + s * 32);
        f16x8 afrag = (s < 2) ? *(const f16x8*)(aa + s * 32)
                              : *(const f16x8*)(ha + (s - 2) * 32);
        dacc = __builtin_amdgcn_mfma_f32_16x16x32_f16(afrag, bfrag, dacc, 0, 0, 0);
    }
    int c = wv * 16 + rp;
    float bb = bl[d * Hd + c];
    #pragma unroll
    for (int j = 0; j < 4; j++) {
        int entw = order[blk + g * 4 + j];
        if (entw >= 0) {
            int n = entw & 0xFFFFF;
            float v = dacc[j] + bb;
            if (relu_out) {
                v = reluf(v);
                hout16[(size_t)n * Hd + c] = __float2half(v);  // next gather's shadow
            }
            hout[(size_t)n * Hd + c] = v;
        }
    }
}

// ---- global add pool (batch_idx is sorted -> mostly single fused atomic) ----
__global__ void k_pool(const float* __restrict__ h, const int* __restrict__ batch,
                       float* __restrict__ g) {
    int wave = rfl((blockIdx.x * 256 + threadIdx.x) >> 6);
    int lane = threadIdx.x & 63;
    int n0 = wave * 4;
    if (n0 >= Nn) return;
    int b0 = batch[n0], b1 = batch[n0 + 1], b2 = batch[n0 + 2], b3 = batch[n0 + 3];
    float v0 = h[(size_t)n0 * Hd + lane];
    float v1 = h[(size_t)(n0 + 1) * Hd + lane];
    float v2 = h[(size_t)(n0 + 2) * Hd + lane];
    float v3 = h[(size_t)(n0 + 3) * Hd + lane];
    if (b0 == b1 && b0 == b2 && b0 == b3) {
        unsafeAtomicAdd(&g[(size_t)b0 * Hd + lane], v0 + v1 + v2 + v3);
    } else {
        unsafeAtomicAdd(&g[(size_t)b0 * Hd + lane], v0);
        unsafeAtomicAdd(&g[(size_t)b1 * Hd + lane], v1);
        unsafeAtomicAdd(&g[(size_t)b2 * Hd + lane], v2);
        unsafeAtomicAdd(&g[(size_t)b3 * Hd + lane], v3);
    }
}

// ---- head: relu(g@lin1+b1)@lin2+b2, one wave per graph ----
__global__ void k_head(const float* __restrict__ g, const float* __restrict__ w1,
                       const float* __restrict__ b1, const float* __restrict__ w2,
                       const float* __restrict__ b2, float* __restrict__ out) {
    __shared__ float t[4][Hd];
    int wv = threadIdx.x >> 6;
    int lane = threadIdx.x & 63;
    int gi = blockIdx.x * 4 + wv;
    float acc = b1[lane];
    for (int k = 0; k < Hd; k++) acc += g[(size_t)gi * Hd + k] * w1[k * Hd + lane];
    t[wv][lane] = reluf(acc);
    __syncthreads();
    if (lane < Od) {
        float o = b2[lane];
        for (int k = 0; k < Hd; k++) o += t[wv][k] * w2[k * Od + lane];
        out[(size_t)gi * Od + lane] = o;
    }
}

extern "C" void kernel_launch(void* const* d_in, const int* in_sizes, int n_in,
                              void* d_out, int out_size, void* d_ws, size_t ws_size,
                              hipStream_t stream) {
    const float* x      = (const float*)d_in[0];
    const float* ea     = (const float*)d_in[1];
    const int*   eidx   = (const int*)d_in[2];
    const int*   batch  = (const int*)d_in[3];
    const float* emb    = (const float*)d_in[4];
    const float* lin1_w = (const float*)d_in[5];
    const float* lin1_b = (const float*)d_in[6];
    const float* lin2_w = (const float*)d_in[7];
    const float* lin2_b = (const float*)d_in[8];
    const float* rgcn_w[2]    = {(const float*)d_in[9],  (const float*)d_in[15]};
    const float* rgcn_root[2] = {(const float*)d_in[10], (const float*)d_in[16]};
    const float* rgcn_b[2]    = {(const float*)d_in[11], (const float*)d_in[17]};
    const float* mf_wl[2]     = {(const float*)d_in[12], (const float*)d_in[18]};
    const float* mf_bl[2]     = {(const float*)d_in[13], (const float*)d_in[19]};
    const float* mf_wr[2]     = {(const float*)d_in[14], (const float*)d_in[20]};

    char* p = (char*)d_ws;
    float* h0    = (float*)p; p += sizeof(float) * (size_t)Nn * Hd;
    float* h1    = (float*)p; p += sizeof(float) * (size_t)Nn * Hd;
    __half* h16a = (__half*)p; p += sizeof(__half) * (size_t)Nn * Hd;
    __half* h16b = (__half*)p; p += sizeof(__half) * (size_t)Nn * Hd;
    float* gbuf  = (float*)p; p += sizeof(float) * (size_t)Ng * Hd;
    __half* wt16 = (__half*)p; p += sizeof(__half) * (size_t)2 * WT_PER_LAYER;
    __half* mfwt16 = (__half*)p; p += sizeof(__half) * (size_t)2 * MFWT_PER_LAYER;
    int* seg     = (int*)p;   p += sizeof(int) * (size_t)Ne;
    int* rank    = (int*)p;   p += sizeof(int) * (size_t)Ne;
    int* ssrc    = (int*)p;   p += sizeof(int) * (size_t)Ne;
    int* cnt     = (int*)p;   p += sizeof(int) * (size_t)NSEG;  // contiguous with bcnt/bfill
    int* bcnt    = (int*)p;   p += sizeof(int) * 16;
    int* bfill   = (int*)p;   p += sizeof(int) * 16;
    int* off     = (int*)p;   p += sizeof(int) * (size_t)(NSEG + 1);
    int* bsum    = (int*)p;   p += sizeof(int) * 1024;
    int* bbase   = (int*)p;   p += sizeof(int) * 16;
    int* order   = (int*)p;   p += sizeof(int) * (size_t)ORDER_SZ;

    hipMemsetAsync(cnt, 0, sizeof(int) * ((size_t)NSEG + 32), stream);
    hipMemsetAsync(gbuf, 0, sizeof(float) * (size_t)Ng * Hd, stream);

    k_prep<<<(PREP_TOTAL + 255) / 256, 256, 0, stream>>>(
        rgcn_w[0], rgcn_root[0], rgcn_w[1], rgcn_root[1],
        mf_wl[0], mf_wr[0], mf_wl[1], mf_wr[1], wt16, mfwt16);
    k_rel_emb<<<NB_RELSEG + NB_EMBED, 256, 0, stream>>>((const float4*)ea, eidx, seg, rank,
                                                        cnt, x, emb, h16a);
    k_scan1<<<SCAN_BLK, 256, 0, stream>>>(cnt, off, bsum, bcnt);
    k_scan2<<<1, 1024, 0, stream>>>(bsum, bcnt, bbase, order);
    k_scan3_bucket<<<SCAN_BLK, 256, 0, stream>>>(off, bsum, (const int4*)cnt, bbase,
                                                 bfill, order);
    k_scatter<<<Ne / 256, 256, 0, stream>>>(eidx, seg, rank, off, ssrc);

    float* h32a = h0;  float* h32b = h1;
    __half* hin16 = h16a;  __half* hout16 = h16b;
    for (int b = 0; b < 2; b++) {
        k_rgcn_fused<<<NB_RG, 256, 0, stream>>>(hin16, off, ssrc, wt16 + b * WT_PER_LAYER,
                                                rgcn_b[b], h32b, hout16);
        k_mf_fused<<<NB_MF, 256, 0, stream>>>(hout16, off, ssrc, order,
                                              mfwt16 + b * MFWT_PER_LAYER, mf_bl[b],
                                              h32a, hin16, b == 0 ? 1 : 0);
        // mf output: fp32 in h32a (pool path), fp16 shadow back in hin16 (b=0 only)
    }
    k_pool<<<Nn / 16, 256, 0, stream>>>(h32a, batch, gbuf);
    k_head<<<Ng / 4, 256, 0, stream>>>(gbuf, lin1_w, lin1_b, lin2_w, lin2_b, (float*)d_out);
}